// Round 4
// baseline (3738.387 us; speedup 1.0000x reference)
//
#include <hip/hip_runtime.h>

#define SEQ    1024
#define EDIM   1024
#define NHEAD  16
#define DHEAD  64
#define NLAYER 12
#define NTOK   4096   // B*S
#define QKVN   2048   // fused q|kv output width

typedef float f32x4  __attribute__((ext_vector_type(4)));
typedef short bf16x8 __attribute__((ext_vector_type(8)));

__device__ __forceinline__ unsigned short f32_to_bf16(float f) {
    union { float f; unsigned u; } v; v.f = f;
    return (unsigned short)((v.u + 0x7fffu + ((v.u >> 16) & 1u)) >> 16);
}

__device__ __forceinline__ void gload_lds16(const unsigned short* g, unsigned short* l) {
    __builtin_amdgcn_global_load_lds((const __attribute__((address_space(1))) void*)g,
                                     (__attribute__((address_space(3))) void*)l, 16, 0, 0);
}

// ---------------- weight prep: W [K][N] f32 -> WT [N][K] bf16, all layers ----------------
__global__ __launch_bounds__(256) void transpose_bf16_k(
    const float* __restrict__ W, unsigned short* __restrict__ WT,
    int K, int N, size_t wStride, size_t wtStride)
{
    __shared__ float tile[32][33];
    const int l = blockIdx.z;
    W  += (size_t)l * wStride;
    WT += (size_t)l * wtStride;
    const int n0 = blockIdx.x * 32, k0 = blockIdx.y * 32;
    const int t = threadIdx.x;
    const int r = t >> 3, c4 = (t & 7) * 4;
    const float4 v = *reinterpret_cast<const float4*>(&W[(size_t)(k0 + r) * N + n0 + c4]);
    tile[r][c4 + 0] = v.x; tile[r][c4 + 1] = v.y;
    tile[r][c4 + 2] = v.z; tile[r][c4 + 3] = v.w;
    __syncthreads();
    ushort4 o;
    o.x = f32_to_bf16(tile[c4 + 0][r]);
    o.y = f32_to_bf16(tile[c4 + 1][r]);
    o.z = f32_to_bf16(tile[c4 + 2][r]);
    o.w = f32_to_bf16(tile[c4 + 3][r]);
    *reinterpret_cast<ushort4*>(&WT[(size_t)(n0 + r) * K + k0 + c4]) = o;
}

// ---------------- bias concat: bqkv[l][0:1024]=bq[l], [1024:2048]=bkv[l] ----------------
__global__ __launch_bounds__(256) void bias_concat_k(
    const float* __restrict__ bq, const float* __restrict__ bkv,
    float* __restrict__ bqkv)
{
    const int l = blockIdx.x, t = threadIdx.x;
    #pragma unroll
    for (int i = 0; i < 4; ++i) {
        const int c = t + i * 256;
        bqkv[(size_t)l * QKVN + c]        = bq[(size_t)l * EDIM + c];
        bqkv[(size_t)l * QKVN + EDIM + c] = bkv[(size_t)l * EDIM + c];
    }
}

// ---------------- embedding: h = wte[x] + wpe[s]  (f32 + bf16 copies) ----------------
__global__ __launch_bounds__(256) void embed_k(
    const int* __restrict__ x, const float* __restrict__ wte,
    const float* __restrict__ wpe, float* __restrict__ h,
    unsigned short* __restrict__ hb)
{
    const int bs  = blockIdx.x;
    const int s   = bs & (SEQ - 1);
    const int tok = x[bs];
    const int c   = threadIdx.x * 4;
    float4 a = *reinterpret_cast<const float4*>(&wte[(size_t)tok * EDIM + c]);
    const float4 p = *reinterpret_cast<const float4*>(&wpe[(size_t)s * EDIM + c]);
    a.x += p.x; a.y += p.y; a.z += p.z; a.w += p.w;
    *reinterpret_cast<float4*>(&h[(size_t)bs * EDIM + c]) = a;
    ushort4 o;
    o.x = f32_to_bf16(a.x); o.y = f32_to_bf16(a.y);
    o.z = f32_to_bf16(a.z); o.w = f32_to_bf16(a.w);
    *reinterpret_cast<ushort4*>(&hb[(size_t)bs * EDIM + c]) = o;
}

// ---------------- layernorm(x1 (+ x2)) -> optional f32 out, optional bf16 out ----------------
template<int WF32, int WBF16>
__global__ __launch_bounds__(256) void add_ln_k(
    const float* __restrict__ x1, const float* __restrict__ x2,
    const float* __restrict__ g, const float* __restrict__ b,
    float* __restrict__ outf, unsigned short* __restrict__ outb)
{
    const int row = blockIdx.x;
    const int t   = threadIdx.x;
    const float* p1 = x1 + (size_t)row * EDIM;
    const float* p2 = x2 ? x2 + (size_t)row * EDIM : nullptr;
    float v[4];
    float s = 0.f, ss = 0.f;
    #pragma unroll
    for (int i = 0; i < 4; ++i) {
        const int c = t + i * 256;
        float a = p1[c];
        if (p2) a += p2[c];
        v[i] = a; s += a; ss += a * a;
    }
    #pragma unroll
    for (int o = 32; o > 0; o >>= 1) {
        s  += __shfl_down(s, o);
        ss += __shfl_down(ss, o);
    }
    __shared__ float rs[4], rss[4];
    const int lane = t & 63, wv = t >> 6;
    if (lane == 0) { rs[wv] = s; rss[wv] = ss; }
    __syncthreads();
    s  = rs[0] + rs[1] + rs[2] + rs[3];
    ss = rss[0] + rss[1] + rss[2] + rss[3];
    const float mean = s * (1.f / EDIM);
    const float var  = ss * (1.f / EDIM) - mean * mean;
    const float inv  = rsqrtf(var + 1e-5f);
    #pragma unroll
    for (int i = 0; i < 4; ++i) {
        const int c = t + i * 256;
        const float y = (v[i] - mean) * inv * g[c] + b[c];
        if (WF32)  outf[(size_t)row * EDIM + c] = y;
        if (WBF16) outb[(size_t)row * EDIM + c] = f32_to_bf16(y);
    }
}

// ---------------- GEMM (m97 structure + XCD swizzle) ----------------
template<int GELU, int OUTBF16>
__global__ __launch_bounds__(256) void gemm_bt_k(
    const unsigned short* __restrict__ A,
    const unsigned short* __restrict__ BT,
    const float* __restrict__ bias, void* __restrict__ Cout,
    int M, int N, int K)
{
    __shared__ unsigned short As[128 * 32];
    __shared__ unsigned short Bs[128 * 32];

    const int t    = threadIdx.x;
    const int lane = t & 63;
    const int wave = t >> 6;
    const int wr   = wave >> 1, wc = wave & 1;
    const int lrow = lane & 15, lgrp = lane >> 4;

    // XCD-aware bijective swizzle (all grids have nwg % 8 == 0)
    const int nbx = gridDim.x;
    int flat = blockIdx.y * nbx + blockIdx.x;
    const int nwg = nbx * gridDim.y;
    flat = (flat & 7) * (nwg >> 3) + (flat >> 3);
    const int row0 = (flat / nbx) * 128, col0 = (flat % nbx) * 128;

    const int srow  = lane >> 2;
    const int skoff = (lane & 3) * 8;
    const unsigned short* aP0 = A  + (size_t)(row0 + 32 * wave + srow) * K + skoff;
    const unsigned short* aP1 = aP0 + (size_t)16 * K;
    const unsigned short* bP0 = BT + (size_t)(col0 + 32 * wave + srow) * K + skoff;
    const unsigned short* bP1 = bP0 + (size_t)16 * K;
    unsigned short* aL0 = As + wave * 1024;
    unsigned short* aL1 = As + wave * 1024 + 512;
    unsigned short* bL0 = Bs + wave * 1024;
    unsigned short* bL1 = Bs + wave * 1024 + 512;

    f32x4 acc[4][4];
    #pragma unroll
    for (int i = 0; i < 4; ++i)
        #pragma unroll
        for (int j = 0; j < 4; ++j)
            acc[i][j] = (f32x4){0.f, 0.f, 0.f, 0.f};

    for (int k0 = 0; k0 < K; k0 += 32) {
        gload_lds16(aP0 + k0, aL0);
        gload_lds16(aP1 + k0, aL1);
        gload_lds16(bP0 + k0, bL0);
        gload_lds16(bP1 + k0, bL1);
        __syncthreads();

        bf16x8 af[4], bf[4];
        #pragma unroll
        for (int m = 0; m < 4; ++m)
            af[m] = *reinterpret_cast<const bf16x8*>(
                &As[(wr * 64 + m * 16 + lrow) * 32 + lgrp * 8]);
        #pragma unroll
        for (int n = 0; n < 4; ++n)
            bf[n] = *reinterpret_cast<const bf16x8*>(
                &Bs[(wc * 64 + n * 16 + lrow) * 32 + lgrp * 8]);

        #pragma unroll
        for (int n = 0; n < 4; ++n)
            #pragma unroll
            for (int m = 0; m < 4; ++m)
                acc[m][n] = __builtin_amdgcn_mfma_f32_16x16x32_bf16(
                    af[m], bf[n], acc[m][n], 0, 0, 0);
        __syncthreads();
    }

    #pragma unroll
    for (int n = 0; n < 4; ++n) {
        const int col = col0 + wc * 64 + n * 16 + lrow;
        const float bv = bias[col];
        #pragma unroll
        for (int m = 0; m < 4; ++m) {
            const int rb = row0 + wr * 64 + m * 16 + lgrp * 4;
            #pragma unroll
            for (int r = 0; r < 4; ++r) {
                float xv = acc[m][n][r] + bv;
                if (GELU) xv = 0.5f * xv * (1.f + erff(xv * 0.70710678118654752f));
                if (OUTBF16)
                    ((unsigned short*)Cout)[(size_t)(rb + r) * N + col] = f32_to_bf16(xv);
                else
                    ((float*)Cout)[(size_t)(rb + r) * N + col] = xv;
            }
        }
    }
}

// ---------------- flash attention: q/kv from fused qkv buffer (stride 2048) ----------------
// KVr[key][d] for QK^T B-frags; KVt[d][key] for PV B-frags (b128, balanced banks).
#define KVP 68
#define KTP 72
__global__ __launch_bounds__(256) void attn_k(
    const unsigned short* __restrict__ qkv, const int* __restrict__ x,
    float* __restrict__ out)
{
    __shared__ unsigned short KVr[64][KVP];
    __shared__ unsigned short KVt[64][KTP];
    __shared__ unsigned short Ps[4][32][KVP];
    __shared__ float maskf[64];

    // XCD swizzle over 512 blocks: tile id T -> (qt, hh, b); 64-chunk per XCD
    int flat = blockIdx.x + 8 * (blockIdx.y + 16 * blockIdx.z);
    flat = (flat & 7) * 64 + (flat >> 3);
    const int qt = flat & 7;
    const int hh = (flat >> 3) & 15;
    const int b  = flat >> 7;

    const int t    = threadIdx.x;
    const int w    = t >> 6;
    const int lane = t & 63;
    const int lrow = lane & 15, lgrp = lane >> 4;

    const unsigned short* qb_  = qkv + ((size_t)b * SEQ) * QKVN + hh * DHEAD;
    const unsigned short* kvb_ = qkv + ((size_t)b * SEQ) * QKVN + EDIM + hh * DHEAD;
    const int* xb = x + b * SEQ;
    const int qrow0 = qt * 128 + w * 32;

    bf16x8 qf[2][2];
    #pragma unroll
    for (int m = 0; m < 2; ++m)
        #pragma unroll
        for (int ks = 0; ks < 2; ++ks)
            qf[m][ks] = *reinterpret_cast<const bf16x8*>(
                qb_ + (size_t)(qrow0 + m * 16 + lrow) * QKVN + ks * 32 + lgrp * 8);

    f32x4 O[2][4];
    float mrun[2][4], lrun[2][4];
    #pragma unroll
    for (int m = 0; m < 2; ++m)
        #pragma unroll
        for (int i = 0; i < 4; ++i) {
            O[m][i] = (f32x4){0.f, 0.f, 0.f, 0.f};
            mrun[m][i] = -3e30f; lrun[m][i] = 0.f;
        }

    for (int kt = 0; kt < SEQ / 64; ++kt) {
        __syncthreads();
        #pragma unroll
        for (int i = 0; i < 4; ++i) {
            const int u2 = t + i * 256;
            const int kr = u2 >> 4, kc = (u2 & 15) * 4;
            const ushort4 v = *reinterpret_cast<const ushort4*>(
                &kvb_[(size_t)(kt * 64 + kr) * QKVN + kc]);
            *reinterpret_cast<ushort4*>(&KVr[kr][kc]) = v;
            KVt[kc + 0][kr] = v.x;
            KVt[kc + 1][kr] = v.y;
            KVt[kc + 2][kr] = v.z;
            KVt[kc + 3][kr] = v.w;
        }
        if (t < 64) maskf[t] = (xb[kt * 64 + t] != 0) ? 1.f : 0.f;
        __syncthreads();

        // QK^T
        f32x4 s[2][4];
        #pragma unroll
        for (int m = 0; m < 2; ++m)
            #pragma unroll
            for (int n = 0; n < 4; ++n) s[m][n] = (f32x4){0.f, 0.f, 0.f, 0.f};
        #pragma unroll
        for (int ks = 0; ks < 2; ++ks)
            #pragma unroll
            for (int n = 0; n < 4; ++n) {
                union { bf16x8 v; ushort4 h[2]; } bb;
                bb.h[0] = *reinterpret_cast<const ushort4*>(
                    &KVr[16 * n + lrow][ks * 32 + lgrp * 8]);
                bb.h[1] = *reinterpret_cast<const ushort4*>(
                    &KVr[16 * n + lrow][ks * 32 + lgrp * 8 + 4]);
                #pragma unroll
                for (int m = 0; m < 2; ++m)
                    s[m][n] = __builtin_amdgcn_mfma_f32_16x16x32_bf16(
                        qf[m][ks], bb.v, s[m][n], 0, 0, 0);
            }

        // mask (replacement semantics)
        #pragma unroll
        for (int n = 0; n < 4; ++n) {
            const float flag = maskf[16 * n + lrow];
            #pragma unroll
            for (int m = 0; m < 2; ++m)
                #pragma unroll
                for (int r = 0; r < 4; ++r)
                    s[m][n][r] = (flag != 0.f) ? s[m][n][r] : -1e9f;
        }

        // online softmax
        #pragma unroll
        for (int m = 0; m < 2; ++m)
            #pragma unroll
            for (int r = 0; r < 4; ++r) {
                float v = fmaxf(fmaxf(s[m][0][r], s[m][1][r]),
                                fmaxf(s[m][2][r], s[m][3][r]));
                #pragma unroll
                for (int o = 1; o < 16; o <<= 1) v = fmaxf(v, __shfl_xor(v, o));
                const float mn = fmaxf(mrun[m][r], v);
                const float fs = __expf(mrun[m][r] - mn);
                mrun[m][r] = mn;
                lrun[m][r] *= fs;
                #pragma unroll
                for (int df = 0; df < 4; ++df) O[m][df][r] *= fs;
            }

        #pragma unroll
        for (int m = 0; m < 2; ++m) {
            float rsum[4] = {0.f, 0.f, 0.f, 0.f};
            #pragma unroll
            for (int n = 0; n < 4; ++n)
                #pragma unroll
                for (int r = 0; r < 4; ++r) {
                    const float p = __expf(s[m][n][r] - mrun[m][r]);
                    rsum[r] += p;
                    Ps[w][m * 16 + 4 * lgrp + r][16 * n + lrow] = f32_to_bf16(p);
                }
            #pragma unroll
            for (int r = 0; r < 4; ++r) {
                float v = rsum[r];
                #pragma unroll
                for (int o = 1; o < 16; o <<= 1) v += __shfl_xor(v, o);
                lrun[m][r] += v;
            }
        }

        // PV: A = P (per-wave LDS), B = KVt b128 fragments
        #pragma unroll
        for (int ks = 0; ks < 2; ++ks) {
            bf16x8 paf[2];
            #pragma unroll
            for (int m = 0; m < 2; ++m) {
                union { bf16x8 v; ushort4 h[2]; } pp;
                pp.h[0] = *reinterpret_cast<const ushort4*>(
                    &Ps[w][m * 16 + lrow][ks * 32 + lgrp * 8]);
                pp.h[1] = *reinterpret_cast<const ushort4*>(
                    &Ps[w][m * 16 + lrow][ks * 32 + lgrp * 8 + 4]);
                paf[m] = pp.v;
            }
            #pragma unroll
            for (int df = 0; df < 4; ++df) {
                const bf16x8 bvf = *reinterpret_cast<const bf16x8*>(
                    &KVt[16 * df + lrow][ks * 32 + lgrp * 8]);
                #pragma unroll
                for (int m = 0; m < 2; ++m)
                    O[m][df] = __builtin_amdgcn_mfma_f32_16x16x32_bf16(
                        paf[m], bvf, O[m][df], 0, 0, 0);
            }
        }
    }

    #pragma unroll
    for (int m = 0; m < 2; ++m)
        #pragma unroll
        for (int r = 0; r < 4; ++r) {
            const float inv = 1.f / lrun[m][r];
            const int row = qrow0 + m * 16 + 4 * lgrp + r;
            float* po = out + ((size_t)b * SEQ + row) * EDIM + hh * DHEAD;
            #pragma unroll
            for (int df = 0; df < 4; ++df)
                po[16 * df + lrow] = O[m][df][r] * inv;
        }
}

// ---------------- driver ----------------
extern "C" void kernel_launch(void* const* d_in, const int* in_sizes, int n_in,
                              void* d_out, int out_size, void* d_ws, size_t ws_size,
                              hipStream_t stream)
{
    (void)in_sizes; (void)n_in; (void)out_size; (void)ws_size;

    const int*   x     = (const int*)  d_in[0];
    const float* wte   = (const float*)d_in[1];
    const float* wpe   = (const float*)d_in[2];
    const float* Wq    = (const float*)d_in[3];
    const float* bq    = (const float*)d_in[4];
    const float* Wkv   = (const float*)d_in[5];
    const float* bkv   = (const float*)d_in[6];
    const float* Wfc   = (const float*)d_in[7];
    const float* bfc   = (const float*)d_in[8];
    const float* Wproj = (const float*)d_in[9];
    const float* bproj = (const float*)d_in[10];
    const float* ln1g  = (const float*)d_in[11];
    const float* ln1b  = (const float*)d_in[12];
    const float* ln2g  = (const float*)d_in[13];
    const float* ln2b  = (const float*)d_in[14];
    const float* lnfg  = (const float*)d_in[15];
    const float* lnfb  = (const float*)d_in[16];

    const size_t MB = 1024 * 1024;
    char* W = (char*)d_ws;
    float*          h     = (float*)(W + 0 * MB);            // 16 MB
    float*          att   = (float*)(W + 16 * MB);           // 16 MB
    float*          mb    = (float*)(W + 32 * MB);           // 16 MB
    unsigned short* hb    = (unsigned short*)(W + 48 * MB);  // 8 MB
    unsigned short* qkv   = (unsigned short*)(W + 56 * MB);  // 16 MB
    unsigned short* ub    = (unsigned short*)(W + 72 * MB);  // 8 MB
    unsigned short* tb    = (unsigned short*)(W + 80 * MB);  // 32 MB
    float*          bqkv  = (float*)(W + 112 * MB);          // 96 KB
    unsigned short* wqkvT = (unsigned short*)(W + 113 * MB); // 48 MB
    unsigned short* wfcT  = (unsigned short*)(W + 161 * MB); // 96 MB
    unsigned short* wpjT  = (unsigned short*)(W + 257 * MB); // 96 MB (end 353 MB)

    // ---- one-time prep (5 launches for all layers)
    bias_concat_k<<<NLAYER, 256, 0, stream>>>(bq, bkv, bqkv);
    transpose_bf16_k<<<dim3(32, 32, NLAYER), 256, 0, stream>>>(
        Wq, wqkvT, EDIM, EDIM, (size_t)EDIM * EDIM, (size_t)QKVN * EDIM);
    transpose_bf16_k<<<dim3(32, 32, NLAYER), 256, 0, stream>>>(
        Wkv, wqkvT + (size_t)EDIM * EDIM, EDIM, EDIM,
        (size_t)EDIM * EDIM, (size_t)QKVN * EDIM);
    transpose_bf16_k<<<dim3(128, 32, NLAYER), 256, 0, stream>>>(
        Wfc, wfcT, EDIM, 4 * EDIM, (size_t)4 * EDIM * EDIM, (size_t)4 * EDIM * EDIM);
    transpose_bf16_k<<<dim3(32, 128, NLAYER), 256, 0, stream>>>(
        Wproj, wpjT, 4 * EDIM, EDIM, (size_t)4 * EDIM * EDIM, (size_t)4 * EDIM * EDIM);

    embed_k<<<NTOK, 256, 0, stream>>>(x, wte, wpe, h, hb);

    for (int l = 0; l < NLAYER; ++l) {
        // fused q|kv GEMM: [4096][2048]
        gemm_bt_k<0, 1><<<dim3(QKVN / 128, NTOK / 128), 256, 0, stream>>>(
            hb, wqkvT + (size_t)l * QKVN * EDIM, bqkv + (size_t)l * QKVN,
            qkv, NTOK, QKVN, EDIM);

        attn_k<<<dim3(SEQ / 128, NHEAD, 4), 256, 0, stream>>>(qkv, x, att);

        add_ln_k<0, 1><<<NTOK, 256, 0, stream>>>(
            h, att, ln1g + l * EDIM, ln1b + l * EDIM, nullptr, ub);

        gemm_bt_k<1, 1><<<dim3(4 * EDIM / 128, NTOK / 128), 256, 0, stream>>>(
            ub, wfcT + (size_t)l * 4 * EDIM * EDIM, bfc + (size_t)l * 4 * EDIM,
            tb, NTOK, 4 * EDIM, EDIM);
        gemm_bt_k<0, 0><<<dim3(EDIM / 128, NTOK / 128), 256, 0, stream>>>(
            tb, wpjT + (size_t)l * 4 * EDIM * EDIM, bproj + (size_t)l * EDIM,
            mb, NTOK, EDIM, 4 * EDIM);

        add_ln_k<1, 1><<<NTOK, 256, 0, stream>>>(
            mb, h, ln2g + l * EDIM, ln2b + l * EDIM, h, hb);
    }

    add_ln_k<1, 0><<<NTOK, 256, 0, stream>>>(
        h, nullptr, lnfg, lnfb, (float*)d_out, nullptr);
}

// Round 5
// 3208.878 us; speedup vs baseline: 1.1650x; 1.1650x over previous
//
#include <hip/hip_runtime.h>

#define SEQ    1024
#define EDIM   1024
#define NHEAD  16
#define DHEAD  64
#define NLAYER 12
#define NTOK   4096   // B*S
#define QKVN   2048   // fused q|kv output width

typedef float f32x4  __attribute__((ext_vector_type(4)));
typedef short bf16x8 __attribute__((ext_vector_type(8)));

__device__ __forceinline__ unsigned short f32_to_bf16(float f) {
    union { float f; unsigned u; } v; v.f = f;
    return (unsigned short)((v.u + 0x7fffu + ((v.u >> 16) & 1u)) >> 16);
}

__device__ __forceinline__ void gload_lds16(const unsigned short* g, unsigned short* l) {
    __builtin_amdgcn_global_load_lds((const __attribute__((address_space(1))) void*)g,
                                     (__attribute__((address_space(3))) void*)l, 16, 0, 0);
}

// ---------------- weight prep: W [K][N] f32 -> WT [N][K] bf16, all layers ----------------
__global__ __launch_bounds__(256) void transpose_bf16_k(
    const float* __restrict__ W, unsigned short* __restrict__ WT,
    int K, int N, size_t wStride, size_t wtStride)
{
    __shared__ float tile[32][33];
    const int l = blockIdx.z;
    W  += (size_t)l * wStride;
    WT += (size_t)l * wtStride;
    const int n0 = blockIdx.x * 32, k0 = blockIdx.y * 32;
    const int t = threadIdx.x;
    const int r = t >> 3, c4 = (t & 7) * 4;
    const float4 v = *reinterpret_cast<const float4*>(&W[(size_t)(k0 + r) * N + n0 + c4]);
    tile[r][c4 + 0] = v.x; tile[r][c4 + 1] = v.y;
    tile[r][c4 + 2] = v.z; tile[r][c4 + 3] = v.w;
    __syncthreads();
    ushort4 o;
    o.x = f32_to_bf16(tile[c4 + 0][r]);
    o.y = f32_to_bf16(tile[c4 + 1][r]);
    o.z = f32_to_bf16(tile[c4 + 2][r]);
    o.w = f32_to_bf16(tile[c4 + 3][r]);
    *reinterpret_cast<ushort4*>(&WT[(size_t)(n0 + r) * K + k0 + c4]) = o;
}

// ---------------- bias concat ----------------
__global__ __launch_bounds__(256) void bias_concat_k(
    const float* __restrict__ bq, const float* __restrict__ bkv,
    float* __restrict__ bqkv)
{
    const int l = blockIdx.x, t = threadIdx.x;
    #pragma unroll
    for (int i = 0; i < 4; ++i) {
        const int c = t + i * 256;
        bqkv[(size_t)l * QKVN + c]        = bq[(size_t)l * EDIM + c];
        bqkv[(size_t)l * QKVN + EDIM + c] = bkv[(size_t)l * EDIM + c];
    }
}

// ---------------- embedding: h = wte[x] + wpe[s]  (f32 + bf16 copies) ----------------
__global__ __launch_bounds__(256) void embed_k(
    const int* __restrict__ x, const float* __restrict__ wte,
    const float* __restrict__ wpe, float* __restrict__ h,
    unsigned short* __restrict__ hb)
{
    const int bs  = blockIdx.x;
    const int s   = bs & (SEQ - 1);
    const int tok = x[bs];
    const int c   = threadIdx.x * 4;
    float4 a = *reinterpret_cast<const float4*>(&wte[(size_t)tok * EDIM + c]);
    const float4 p = *reinterpret_cast<const float4*>(&wpe[(size_t)s * EDIM + c]);
    a.x += p.x; a.y += p.y; a.z += p.z; a.w += p.w;
    *reinterpret_cast<float4*>(&h[(size_t)bs * EDIM + c]) = a;
    ushort4 o;
    o.x = f32_to_bf16(a.x); o.y = f32_to_bf16(a.y);
    o.z = f32_to_bf16(a.z); o.w = f32_to_bf16(a.w);
    *reinterpret_cast<ushort4*>(&hb[(size_t)bs * EDIM + c]) = o;
}

// ---------------- layernorm(x1 (+x2) (+x3)) -> optional f32 / bf16 out, float4 path ----------------
template<int NADD, int WF32, int WBF16>
__global__ __launch_bounds__(256) void add_ln_k(
    const float* __restrict__ x1, const float* __restrict__ x2,
    const float* __restrict__ x3, const float* __restrict__ g,
    const float* __restrict__ b, float* __restrict__ outf,
    unsigned short* __restrict__ outb)
{
    const int row = blockIdx.x;
    const int t   = threadIdx.x;
    const int c   = t * 4;
    const size_t base = (size_t)row * EDIM + c;
    float4 a = *reinterpret_cast<const float4*>(x1 + base);
    if (NADD >= 2) {
        const float4 v = *reinterpret_cast<const float4*>(x2 + base);
        a.x += v.x; a.y += v.y; a.z += v.z; a.w += v.w;
    }
    if (NADD >= 3) {
        const float4 v = *reinterpret_cast<const float4*>(x3 + base);
        a.x += v.x; a.y += v.y; a.z += v.z; a.w += v.w;
    }
    float s  = a.x + a.y + a.z + a.w;
    float ss = a.x * a.x + a.y * a.y + a.z * a.z + a.w * a.w;
    #pragma unroll
    for (int o = 32; o > 0; o >>= 1) {
        s  += __shfl_down(s, o);
        ss += __shfl_down(ss, o);
    }
    __shared__ float rs[4], rss[4];
    const int lane = t & 63, wv = t >> 6;
    if (lane == 0) { rs[wv] = s; rss[wv] = ss; }
    __syncthreads();
    s  = rs[0] + rs[1] + rs[2] + rs[3];
    ss = rss[0] + rss[1] + rss[2] + rss[3];
    const float mean = s * (1.f / EDIM);
    const float var  = ss * (1.f / EDIM) - mean * mean;
    const float inv  = rsqrtf(var + 1e-5f);
    const float4 gv = *reinterpret_cast<const float4*>(g + c);
    const float4 bv = *reinterpret_cast<const float4*>(b + c);
    float4 y;
    y.x = (a.x - mean) * inv * gv.x + bv.x;
    y.y = (a.y - mean) * inv * gv.y + bv.y;
    y.z = (a.z - mean) * inv * gv.z + bv.z;
    y.w = (a.w - mean) * inv * gv.w + bv.w;
    if (WF32) *reinterpret_cast<float4*>(outf + base) = y;
    if (WBF16) {
        ushort4 o;
        o.x = f32_to_bf16(y.x); o.y = f32_to_bf16(y.y);
        o.z = f32_to_bf16(y.z); o.w = f32_to_bf16(y.w);
        *reinterpret_cast<ushort4*>(outb + base) = o;
    }
}

// ---------------- GEMM (m97 structure + XCD swizzle + optional split-K over z) ----------------
template<int GELU, int OUTBF16>
__global__ __launch_bounds__(256) void gemm_bt_k(
    const unsigned short* __restrict__ A,
    const unsigned short* __restrict__ BT,
    const float* __restrict__ bias, void* __restrict__ Cout,
    void* __restrict__ Cout2, int M, int N, int K)
{
    __shared__ unsigned short As[128 * 32];
    __shared__ unsigned short Bs[128 * 32];

    const int t    = threadIdx.x;
    const int lane = t & 63;
    const int wave = t >> 6;
    const int wr   = wave >> 1, wc = wave & 1;
    const int lrow = lane & 15, lgrp = lane >> 4;

    // XCD-aware bijective swizzle per z-slice (nwg % 8 == 0 for all grids used)
    const int nbx = gridDim.x;
    int flat = blockIdx.y * nbx + blockIdx.x;
    const int nwg = nbx * gridDim.y;
    flat = (flat & 7) * (nwg >> 3) + (flat >> 3);
    const int row0 = (flat / nbx) * 128, col0 = (flat % nbx) * 128;

    const int kspan = K / gridDim.z;
    const int koff  = blockIdx.z * kspan;

    const int srow  = lane >> 2;
    const int skoff = (lane & 3) * 8;
    const unsigned short* aP0 = A  + (size_t)(row0 + 32 * wave + srow) * K + skoff;
    const unsigned short* aP1 = aP0 + (size_t)16 * K;
    const unsigned short* bP0 = BT + (size_t)(col0 + 32 * wave + srow) * K + skoff;
    const unsigned short* bP1 = bP0 + (size_t)16 * K;
    unsigned short* aL0 = As + wave * 1024;
    unsigned short* aL1 = As + wave * 1024 + 512;
    unsigned short* bL0 = Bs + wave * 1024;
    unsigned short* bL1 = Bs + wave * 1024 + 512;

    f32x4 acc[4][4];
    #pragma unroll
    for (int i = 0; i < 4; ++i)
        #pragma unroll
        for (int j = 0; j < 4; ++j)
            acc[i][j] = (f32x4){0.f, 0.f, 0.f, 0.f};

    for (int k0 = koff; k0 < koff + kspan; k0 += 32) {
        gload_lds16(aP0 + k0, aL0);
        gload_lds16(aP1 + k0, aL1);
        gload_lds16(bP0 + k0, bL0);
        gload_lds16(bP1 + k0, bL1);
        __syncthreads();

        bf16x8 af[4], bf[4];
        #pragma unroll
        for (int m = 0; m < 4; ++m)
            af[m] = *reinterpret_cast<const bf16x8*>(
                &As[(wr * 64 + m * 16 + lrow) * 32 + lgrp * 8]);
        #pragma unroll
        for (int n = 0; n < 4; ++n)
            bf[n] = *reinterpret_cast<const bf16x8*>(
                &Bs[(wc * 64 + n * 16 + lrow) * 32 + lgrp * 8]);

        #pragma unroll
        for (int n = 0; n < 4; ++n)
            #pragma unroll
            for (int m = 0; m < 4; ++m)
                acc[m][n] = __builtin_amdgcn_mfma_f32_16x16x32_bf16(
                    af[m], bf[n], acc[m][n], 0, 0, 0);
        __syncthreads();
    }

    const int z = blockIdx.z;
    #pragma unroll
    for (int n = 0; n < 4; ++n) {
        const int col = col0 + wc * 64 + n * 16 + lrow;
        const float bv = (z == 0) ? bias[col] : 0.f;
        #pragma unroll
        for (int m = 0; m < 4; ++m) {
            const int rb = row0 + wr * 64 + m * 16 + lgrp * 4;
            #pragma unroll
            for (int r = 0; r < 4; ++r) {
                float xv = acc[m][n][r] + bv;
                if (GELU) xv = 0.5f * xv * (1.f + erff(xv * 0.70710678118654752f));
                if (OUTBF16) {
                    ((unsigned short*)Cout)[(size_t)(rb + r) * N + col] = f32_to_bf16(xv);
                } else {
                    float* dst = (z == 0) ? (float*)Cout : (float*)Cout2;
                    dst[(size_t)(rb + r) * N + col] = xv;
                }
            }
        }
    }
}

// ---------------- flash attention: q/kv from fused qkv buffer (stride 2048) ----------------
// KVr[key][d] (pad 68) for QK^T; KVt = d-major, stride 128B, XOR-swizzled (conflict-free
// for both column-major staging writes and PV b128 reads: s=(d^(d>>3))&7, byte^=s<<4).
#define KVP 68
__global__ __launch_bounds__(256) void attn_k(
    const unsigned short* __restrict__ qkv, const int* __restrict__ x,
    float* __restrict__ out)
{
    __shared__ unsigned short KVr[64][KVP];
    __shared__ unsigned short KVt[64 * 64];
    __shared__ unsigned short Ps[4][32][KVP];
    __shared__ float maskf[64];

    int flat = blockIdx.x + 8 * (blockIdx.y + 16 * blockIdx.z);
    flat = (flat & 7) * 64 + (flat >> 3);
    const int qt = flat & 7;
    const int hh = (flat >> 3) & 15;
    const int b  = flat >> 7;

    const int t    = threadIdx.x;
    const int w    = t >> 6;
    const int lane = t & 63;
    const int lrow = lane & 15, lgrp = lane >> 4;

    const unsigned short* qb_  = qkv + ((size_t)b * SEQ) * QKVN + hh * DHEAD;
    const unsigned short* kvb_ = qkv + ((size_t)b * SEQ) * QKVN + EDIM + hh * DHEAD;
    const int* xb = x + b * SEQ;
    const int qrow0 = qt * 128 + w * 32;

    bf16x8 qf[2][2];
    #pragma unroll
    for (int m = 0; m < 2; ++m)
        #pragma unroll
        for (int ks = 0; ks < 2; ++ks)
            qf[m][ks] = *reinterpret_cast<const bf16x8*>(
                qb_ + (size_t)(qrow0 + m * 16 + lrow) * QKVN + ks * 32 + lgrp * 8);

    f32x4 O[2][4];
    float mrun[2][4], lrun[2][4];
    #pragma unroll
    for (int m = 0; m < 2; ++m)
        #pragma unroll
        for (int i = 0; i < 4; ++i) {
            O[m][i] = (f32x4){0.f, 0.f, 0.f, 0.f};
            mrun[m][i] = -3e30f; lrun[m][i] = 0.f;
        }

    for (int kt = 0; kt < SEQ / 64; ++kt) {
        __syncthreads();
        #pragma unroll
        for (int i = 0; i < 4; ++i) {
            const int u2 = t + i * 256;
            const int kr = u2 >> 4, kc = (u2 & 15) * 4;
            const ushort4 v = *reinterpret_cast<const ushort4*>(
                &kvb_[(size_t)(kt * 64 + kr) * QKVN + kc]);
            *reinterpret_cast<ushort4*>(&KVr[kr][kc]) = v;
            const unsigned short comp[4] = {v.x, v.y, v.z, v.w};
            #pragma unroll
            for (int j = 0; j < 4; ++j) {
                const int d = kc + j;
                const int sw = (d ^ (d >> 3)) & 7;
                KVt[(d * 128 + ((kr * 2) ^ (sw << 4))) >> 1] = comp[j];
            }
        }
        if (t < 64) maskf[t] = (xb[kt * 64 + t] != 0) ? 1.f : 0.f;
        __syncthreads();

        // QK^T
        f32x4 s[2][4];
        #pragma unroll
        for (int m = 0; m < 2; ++m)
            #pragma unroll
            for (int n = 0; n < 4; ++n) s[m][n] = (f32x4){0.f, 0.f, 0.f, 0.f};
        #pragma unroll
        for (int ks = 0; ks < 2; ++ks)
            #pragma unroll
            for (int n = 0; n < 4; ++n) {
                union { bf16x8 v; ushort4 h[2]; } bb;
                bb.h[0] = *reinterpret_cast<const ushort4*>(
                    &KVr[16 * n + lrow][ks * 32 + lgrp * 8]);
                bb.h[1] = *reinterpret_cast<const ushort4*>(
                    &KVr[16 * n + lrow][ks * 32 + lgrp * 8 + 4]);
                #pragma unroll
                for (int m = 0; m < 2; ++m)
                    s[m][n] = __builtin_amdgcn_mfma_f32_16x16x32_bf16(
                        qf[m][ks], bb.v, s[m][n], 0, 0, 0);
            }

        // mask (replacement semantics)
        #pragma unroll
        for (int n = 0; n < 4; ++n) {
            const float flag = maskf[16 * n + lrow];
            #pragma unroll
            for (int m = 0; m < 2; ++m)
                #pragma unroll
                for (int r = 0; r < 4; ++r)
                    s[m][n][r] = (flag != 0.f) ? s[m][n][r] : -1e9f;
        }

        // online softmax
        #pragma unroll
        for (int m = 0; m < 2; ++m)
            #pragma unroll
            for (int r = 0; r < 4; ++r) {
                float v = fmaxf(fmaxf(s[m][0][r], s[m][1][r]),
                                fmaxf(s[m][2][r], s[m][3][r]));
                #pragma unroll
                for (int o = 1; o < 16; o <<= 1) v = fmaxf(v, __shfl_xor(v, o));
                const float mn = fmaxf(mrun[m][r], v);
                const float fs = __expf(mrun[m][r] - mn);
                mrun[m][r] = mn;
                lrun[m][r] *= fs;
                #pragma unroll
                for (int df = 0; df < 4; ++df) O[m][df][r] *= fs;
            }

        #pragma unroll
        for (int m = 0; m < 2; ++m) {
            float rsum[4] = {0.f, 0.f, 0.f, 0.f};
            #pragma unroll
            for (int n = 0; n < 4; ++n)
                #pragma unroll
                for (int r = 0; r < 4; ++r) {
                    const float p = __expf(s[m][n][r] - mrun[m][r]);
                    rsum[r] += p;
                    Ps[w][m * 16 + 4 * lgrp + r][16 * n + lrow] = f32_to_bf16(p);
                }
            #pragma unroll
            for (int r = 0; r < 4; ++r) {
                float v = rsum[r];
                #pragma unroll
                for (int o = 1; o < 16; o <<= 1) v += __shfl_xor(v, o);
                lrun[m][r] += v;
            }
        }

        // PV: A = P (per-wave LDS), B = KVt swizzled b128 fragments
        #pragma unroll
        for (int ks = 0; ks < 2; ++ks) {
            bf16x8 paf[2];
            #pragma unroll
            for (int m = 0; m < 2; ++m) {
                union { bf16x8 v; ushort4 h[2]; } pp;
                pp.h[0] = *reinterpret_cast<const ushort4*>(
                    &Ps[w][m * 16 + lrow][ks * 32 + lgrp * 8]);
                pp.h[1] = *reinterpret_cast<const ushort4*>(
                    &Ps[w][m * 16 + lrow][ks * 32 + lgrp * 8 + 4]);
                paf[m] = pp.v;
            }
            #pragma unroll
            for (int df = 0; df < 4; ++df) {
                const int d  = 16 * df + lrow;
                const int sw = (d ^ (d >> 3)) & 7;
                const bf16x8 bvf = *reinterpret_cast<const bf16x8*>(
                    &KVt[(d * 128 + ((ks * 64 + lgrp * 16) ^ (sw << 4))) >> 1]);
                #pragma unroll
                for (int m = 0; m < 2; ++m)
                    O[m][df] = __builtin_amdgcn_mfma_f32_16x16x32_bf16(
                        paf[m], bvf, O[m][df], 0, 0, 0);
            }
        }
    }

    #pragma unroll
    for (int m = 0; m < 2; ++m)
        #pragma unroll
        for (int r = 0; r < 4; ++r) {
            const float inv = 1.f / lrun[m][r];
            const int row = qrow0 + m * 16 + 4 * lgrp + r;
            float* po = out + ((size_t)b * SEQ + row) * EDIM + hh * DHEAD;
            #pragma unroll
            for (int df = 0; df < 4; ++df)
                po[16 * df + lrow] = O[m][df][r] * inv;
        }
}

// ---------------- driver ----------------
extern "C" void kernel_launch(void* const* d_in, const int* in_sizes, int n_in,
                              void* d_out, int out_size, void* d_ws, size_t ws_size,
                              hipStream_t stream)
{
    (void)in_sizes; (void)n_in; (void)out_size; (void)ws_size;

    const int*   x     = (const int*)  d_in[0];
    const float* wte   = (const float*)d_in[1];
    const float* wpe   = (const float*)d_in[2];
    const float* Wq    = (const float*)d_in[3];
    const float* bq    = (const float*)d_in[4];
    const float* Wkv   = (const float*)d_in[5];
    const float* bkv   = (const float*)d_in[6];
    const float* Wfc   = (const float*)d_in[7];
    const float* bfc   = (const float*)d_in[8];
    const float* Wproj = (const float*)d_in[9];
    const float* bproj = (const float*)d_in[10];
    const float* ln1g  = (const float*)d_in[11];
    const float* ln1b  = (const float*)d_in[12];
    const float* ln2g  = (const float*)d_in[13];
    const float* ln2b  = (const float*)d_in[14];
    const float* lnfg  = (const float*)d_in[15];
    const float* lnfb  = (const float*)d_in[16];

    const size_t MB = 1024 * 1024;
    char* W = (char*)d_ws;
    float*          h     = (float*)(W + 0 * MB);            // 16 MB
    float*          att   = (float*)(W + 16 * MB);           // 16 MB (reused as mb2)
    float*          mb    = (float*)(W + 32 * MB);           // 16 MB
    unsigned short* hb    = (unsigned short*)(W + 48 * MB);  // 8 MB
    unsigned short* qkv   = (unsigned short*)(W + 56 * MB);  // 16 MB
    unsigned short* ub    = (unsigned short*)(W + 72 * MB);  // 8 MB
    unsigned short* tb    = (unsigned short*)(W + 80 * MB);  // 32 MB
    float*          bqkv  = (float*)(W + 112 * MB);          // 96 KB
    unsigned short* wqkvT = (unsigned short*)(W + 113 * MB); // 48 MB
    unsigned short* wfcT  = (unsigned short*)(W + 161 * MB); // 96 MB
    unsigned short* wpjT  = (unsigned short*)(W + 257 * MB); // 96 MB (end 353 MB)

    // ---- one-time prep
    bias_concat_k<<<NLAYER, 256, 0, stream>>>(bq, bkv, bqkv);
    transpose_bf16_k<<<dim3(32, 32, NLAYER), 256, 0, stream>>>(
        Wq, wqkvT, EDIM, EDIM, (size_t)EDIM * EDIM, (size_t)QKVN * EDIM);
    transpose_bf16_k<<<dim3(32, 32, NLAYER), 256, 0, stream>>>(
        Wkv, wqkvT + (size_t)EDIM * EDIM, EDIM, EDIM,
        (size_t)EDIM * EDIM, (size_t)QKVN * EDIM);
    transpose_bf16_k<<<dim3(128, 32, NLAYER), 256, 0, stream>>>(
        Wfc, wfcT, EDIM, 4 * EDIM, (size_t)4 * EDIM * EDIM, (size_t)4 * EDIM * EDIM);
    transpose_bf16_k<<<dim3(32, 128, NLAYER), 256, 0, stream>>>(
        Wproj, wpjT, 4 * EDIM, EDIM, (size_t)4 * EDIM * EDIM, (size_t)4 * EDIM * EDIM);

    embed_k<<<NTOK, 256, 0, stream>>>(x, wte, wpe, h, hb);

    for (int l = 0; l < NLAYER; ++l) {
        // fused q|kv GEMM: [4096][2048]
        gemm_bt_k<0, 1><<<dim3(QKVN / 128, NTOK / 128), 256, 0, stream>>>(
            hb, wqkvT + (size_t)l * QKVN * EDIM, bqkv + (size_t)l * QKVN,
            qkv, nullptr, NTOK, QKVN, EDIM);

        attn_k<<<dim3(SEQ / 128, NHEAD, 4), 256, 0, stream>>>(qkv, x, att);

        add_ln_k<2, 0, 1><<<NTOK, 256, 0, stream>>>(
            h, att, nullptr, ln1g + l * EDIM, ln1b + l * EDIM, nullptr, ub);

        gemm_bt_k<1, 1><<<dim3(4 * EDIM / 128, NTOK / 128), 256, 0, stream>>>(
            ub, wfcT + (size_t)l * 4 * EDIM * EDIM, bfc + (size_t)l * 4 * EDIM,
            tb, nullptr, NTOK, 4 * EDIM, EDIM);

        // proj split-K=2: z=0 -> mb (with bias), z=1 -> att buffer (partial)
        gemm_bt_k<0, 0><<<dim3(EDIM / 128, NTOK / 128, 2), 256, 0, stream>>>(
            tb, wpjT + (size_t)l * 4 * EDIM * EDIM, bproj + (size_t)l * EDIM,
            mb, att, NTOK, EDIM, 4 * EDIM);

        add_ln_k<3, 1, 1><<<NTOK, 256, 0, stream>>>(
            mb, att, h, ln2g + l * EDIM, ln2b + l * EDIM, h, hb);
    }

    add_ln_k<1, 1, 0><<<NTOK, 256, 0, stream>>>(
        h, nullptr, nullptr, lnfg, lnfb, (float*)d_out, nullptr);
}

// Round 6
// 2951.861 us; speedup vs baseline: 1.2665x; 1.0871x over previous
//
#include <hip/hip_runtime.h>

#define SEQ    1024
#define EDIM   1024
#define NHEAD  16
#define DHEAD  64
#define NLAYER 12
#define NTOK   4096   // B*S
#define QKVN   2048   // fused q|kv output width

typedef float f32x4  __attribute__((ext_vector_type(4)));
typedef short bf16x8 __attribute__((ext_vector_type(8)));

__device__ __forceinline__ unsigned short f32_to_bf16(float f) {
    union { float f; unsigned u; } v; v.f = f;
    return (unsigned short)((v.u + 0x7fffu + ((v.u >> 16) & 1u)) >> 16);
}

__device__ __forceinline__ void gload_lds16(const unsigned short* g, unsigned short* l) {
    __builtin_amdgcn_global_load_lds((const __attribute__((address_space(1))) void*)g,
                                     (__attribute__((address_space(3))) void*)l, 16, 0, 0);
}

#define BARRIER() do { __builtin_amdgcn_s_barrier(); asm volatile("" ::: "memory"); } while (0)

// ---------------- weight prep: W [K][N] f32 -> WT [N][K] bf16, all layers ----------------
__global__ __launch_bounds__(256) void transpose_bf16_k(
    const float* __restrict__ W, unsigned short* __restrict__ WT,
    int K, int N, size_t wStride, size_t wtStride)
{
    __shared__ float tile[32][33];
    const int l = blockIdx.z;
    W  += (size_t)l * wStride;
    WT += (size_t)l * wtStride;
    const int n0 = blockIdx.x * 32, k0 = blockIdx.y * 32;
    const int t = threadIdx.x;
    const int r = t >> 3, c4 = (t & 7) * 4;
    const float4 v = *reinterpret_cast<const float4*>(&W[(size_t)(k0 + r) * N + n0 + c4]);
    tile[r][c4 + 0] = v.x; tile[r][c4 + 1] = v.y;
    tile[r][c4 + 2] = v.z; tile[r][c4 + 3] = v.w;
    __syncthreads();
    ushort4 o;
    o.x = f32_to_bf16(tile[c4 + 0][r]);
    o.y = f32_to_bf16(tile[c4 + 1][r]);
    o.z = f32_to_bf16(tile[c4 + 2][r]);
    o.w = f32_to_bf16(tile[c4 + 3][r]);
    *reinterpret_cast<ushort4*>(&WT[(size_t)(n0 + r) * K + k0 + c4]) = o;
}

// ---------------- bias concat ----------------
__global__ __launch_bounds__(256) void bias_concat_k(
    const float* __restrict__ bq, const float* __restrict__ bkv,
    float* __restrict__ bqkv)
{
    const int l = blockIdx.x, t = threadIdx.x;
    #pragma unroll
    for (int i = 0; i < 4; ++i) {
        const int c = t + i * 256;
        bqkv[(size_t)l * QKVN + c]        = bq[(size_t)l * EDIM + c];
        bqkv[(size_t)l * QKVN + EDIM + c] = bkv[(size_t)l * EDIM + c];
    }
}

// ---------------- embedding ----------------
__global__ __launch_bounds__(256) void embed_k(
    const int* __restrict__ x, const float* __restrict__ wte,
    const float* __restrict__ wpe, float* __restrict__ h,
    unsigned short* __restrict__ hb)
{
    const int bs  = blockIdx.x;
    const int s   = bs & (SEQ - 1);
    const int tok = x[bs];
    const int c   = threadIdx.x * 4;
    float4 a = *reinterpret_cast<const float4*>(&wte[(size_t)tok * EDIM + c]);
    const float4 p = *reinterpret_cast<const float4*>(&wpe[(size_t)s * EDIM + c]);
    a.x += p.x; a.y += p.y; a.z += p.z; a.w += p.w;
    *reinterpret_cast<float4*>(&h[(size_t)bs * EDIM + c]) = a;
    ushort4 o;
    o.x = f32_to_bf16(a.x); o.y = f32_to_bf16(a.y);
    o.z = f32_to_bf16(a.z); o.w = f32_to_bf16(a.w);
    *reinterpret_cast<ushort4*>(&hb[(size_t)bs * EDIM + c]) = o;
}

// ---------------- layernorm(x1 (+x2) (+x3)) ----------------
template<int NADD, int WF32, int WBF16>
__global__ __launch_bounds__(256) void add_ln_k(
    const float* __restrict__ x1, const float* __restrict__ x2,
    const float* __restrict__ x3, const float* __restrict__ g,
    const float* __restrict__ b, float* __restrict__ outf,
    unsigned short* __restrict__ outb)
{
    const int row = blockIdx.x;
    const int t   = threadIdx.x;
    const int c   = t * 4;
    const size_t base = (size_t)row * EDIM + c;
    float4 a = *reinterpret_cast<const float4*>(x1 + base);
    if (NADD >= 2) {
        const float4 v = *reinterpret_cast<const float4*>(x2 + base);
        a.x += v.x; a.y += v.y; a.z += v.z; a.w += v.w;
    }
    if (NADD >= 3) {
        const float4 v = *reinterpret_cast<const float4*>(x3 + base);
        a.x += v.x; a.y += v.y; a.z += v.z; a.w += v.w;
    }
    float s  = a.x + a.y + a.z + a.w;
    float ss = a.x * a.x + a.y * a.y + a.z * a.z + a.w * a.w;
    #pragma unroll
    for (int o = 32; o > 0; o >>= 1) {
        s  += __shfl_down(s, o);
        ss += __shfl_down(ss, o);
    }
    __shared__ float rs[4], rss[4];
    const int lane = t & 63, wv = t >> 6;
    if (lane == 0) { rs[wv] = s; rss[wv] = ss; }
    __syncthreads();
    s  = rs[0] + rs[1] + rs[2] + rs[3];
    ss = rss[0] + rss[1] + rss[2] + rss[3];
    const float mean = s * (1.f / EDIM);
    const float var  = ss * (1.f / EDIM) - mean * mean;
    const float inv  = rsqrtf(var + 1e-5f);
    const float4 gv = *reinterpret_cast<const float4*>(g + c);
    const float4 bv = *reinterpret_cast<const float4*>(b + c);
    float4 y;
    y.x = (a.x - mean) * inv * gv.x + bv.x;
    y.y = (a.y - mean) * inv * gv.y + bv.y;
    y.z = (a.z - mean) * inv * gv.z + bv.z;
    y.w = (a.w - mean) * inv * gv.w + bv.w;
    if (WF32) *reinterpret_cast<float4*>(outf + base) = y;
    if (WBF16) {
        ushort4 o;
        o.x = f32_to_bf16(y.x); o.y = f32_to_bf16(y.y);
        o.z = f32_to_bf16(y.z); o.w = f32_to_bf16(y.w);
        *reinterpret_cast<ushort4*>(outb + base) = o;
    }
}

// ---------------- GEMM m97 (128^2, used for qkv + proj split-K) ----------------
template<int GELU, int OUTBF16>
__global__ __launch_bounds__(256) void gemm_bt_k(
    const unsigned short* __restrict__ A,
    const unsigned short* __restrict__ BT,
    const float* __restrict__ bias, void* __restrict__ Cout,
    void* __restrict__ Cout2, int M, int N, int K)
{
    __shared__ unsigned short As[128 * 32];
    __shared__ unsigned short Bs[128 * 32];

    const int t    = threadIdx.x;
    const int lane = t & 63;
    const int wave = t >> 6;
    const int wr   = wave >> 1, wc = wave & 1;
    const int lrow = lane & 15, lgrp = lane >> 4;

    const int nbx = gridDim.x;
    int flat = blockIdx.y * nbx + blockIdx.x;
    const int nwg = nbx * gridDim.y;
    flat = (flat & 7) * (nwg >> 3) + (flat >> 3);
    const int row0 = (flat / nbx) * 128, col0 = (flat % nbx) * 128;

    const int kspan = K / gridDim.z;
    const int koff  = blockIdx.z * kspan;

    const int srow  = lane >> 2;
    const int skoff = (lane & 3) * 8;
    const unsigned short* aP0 = A  + (size_t)(row0 + 32 * wave + srow) * K + skoff;
    const unsigned short* aP1 = aP0 + (size_t)16 * K;
    const unsigned short* bP0 = BT + (size_t)(col0 + 32 * wave + srow) * K + skoff;
    const unsigned short* bP1 = bP0 + (size_t)16 * K;
    unsigned short* aL0 = As + wave * 1024;
    unsigned short* aL1 = As + wave * 1024 + 512;
    unsigned short* bL0 = Bs + wave * 1024;
    unsigned short* bL1 = Bs + wave * 1024 + 512;

    f32x4 acc[4][4];
    #pragma unroll
    for (int i = 0; i < 4; ++i)
        #pragma unroll
        for (int j = 0; j < 4; ++j)
            acc[i][j] = (f32x4){0.f, 0.f, 0.f, 0.f};

    for (int k0 = koff; k0 < koff + kspan; k0 += 32) {
        gload_lds16(aP0 + k0, aL0);
        gload_lds16(aP1 + k0, aL1);
        gload_lds16(bP0 + k0, bL0);
        gload_lds16(bP1 + k0, bL1);
        __syncthreads();

        bf16x8 af[4], bf[4];
        #pragma unroll
        for (int m = 0; m < 4; ++m)
            af[m] = *reinterpret_cast<const bf16x8*>(
                &As[(wr * 64 + m * 16 + lrow) * 32 + lgrp * 8]);
        #pragma unroll
        for (int n = 0; n < 4; ++n)
            bf[n] = *reinterpret_cast<const bf16x8*>(
                &Bs[(wc * 64 + n * 16 + lrow) * 32 + lgrp * 8]);

        #pragma unroll
        for (int n = 0; n < 4; ++n)
            #pragma unroll
            for (int m = 0; m < 4; ++m)
                acc[m][n] = __builtin_amdgcn_mfma_f32_16x16x32_bf16(
                    af[m], bf[n], acc[m][n], 0, 0, 0);
        __syncthreads();
    }

    const int z = blockIdx.z;
    #pragma unroll
    for (int n = 0; n < 4; ++n) {
        const int col = col0 + wc * 64 + n * 16 + lrow;
        const float bv = (z == 0) ? bias[col] : 0.f;
        #pragma unroll
        for (int m = 0; m < 4; ++m) {
            const int rb = row0 + wr * 64 + m * 16 + lgrp * 4;
            #pragma unroll
            for (int r = 0; r < 4; ++r) {
                float xv = acc[m][n][r] + bv;
                if (GELU) xv = 0.5f * xv * (1.f + erff(xv * 0.70710678118654752f));
                if (OUTBF16) {
                    ((unsigned short*)Cout)[(size_t)(rb + r) * N + col] = f32_to_bf16(xv);
                } else {
                    float* dst = (z == 0) ? (float*)Cout : (float*)Cout2;
                    dst[(size_t)(rb + r) * N + col] = xv;
                }
            }
        }
    }
}

// ---------------- GEMM 256^2 8-phase (T2+T3+T4+T5), used for FC ----------------
// 512 thr = 8 waves (2M x 4N); BK=64; LDS 128 KiB (A,B double-buffered 256x64 bf16);
// swizzle: byte ^= ((row&7)<<4) applied to global source (staging) and ds_read.
// vmcnt counted at tile boundaries only (phases 4/8), before the barrier.
template<int GELU>
__global__ __launch_bounds__(512) void gemm256_k(
    const unsigned short* __restrict__ A,
    const unsigned short* __restrict__ BT,
    const float* __restrict__ bias, unsigned short* __restrict__ C,
    int M, int N, int K)
{
    __shared__ unsigned short sh[65536];          // A: [0,32768) B: [32768,65536)
    unsigned short* Asm = sh;
    unsigned short* Bsm = sh + 32768;

    const int tid  = threadIdx.x;
    const int lane = tid & 63;
    const int wave = tid >> 6;
    const int wm   = wave >> 2;          // 0..1
    const int wn   = wave & 3;           // 0..3
    const int lrow = lane & 15, lgrp = lane >> 4;

    // XCD-chunked bijective swizzle (grid multiple of 8)
    const int ntc = N >> 8;
    const int nwg = gridDim.x;
    int flat = (blockIdx.x & 7) * (nwg >> 3) + (blockIdx.x >> 3);
    const int row0 = (flat / ntc) * 256;
    const int col0 = (flat % ntc) * 256;
    const int NT = K >> 6;

    f32x4 acc[8][4];
    #pragma unroll
    for (int i = 0; i < 8; ++i)
        #pragma unroll
        for (int j = 0; j < 4; ++j)
            acc[i][j] = (f32x4){0.f, 0.f, 0.f, 0.f};

    // stage one 16KB half-tile (128 rows x 64 cols) : 2 x gload16/thread,
    // source pre-swizzled so LDS content at phys addr = logical ^ ((row&7)<<4)
    auto stage_half = [&](const unsigned short* g, unsigned short* l) {
        #pragma unroll
        for (int c = 0; c < 2; ++c) {
            const int d = (tid + c * 512) * 16;            // byte 0..16383
            const int L = d ^ (((d >> 7) & 7) << 4);
            gload_lds16(g + (size_t)(L >> 7) * K + ((L & 127) >> 1), l + (d >> 1));
        }
    };
    auto stageA = [&](int buf, int kt, int h) {
        stage_half(A + (size_t)(row0 + h * 128) * K + kt * 64,
                   Asm + buf * 16384 + h * 8192);
    };
    auto stageB = [&](int buf, int kt, int h) {
        stage_half(BT + (size_t)(col0 + h * 128) * K + kt * 64,
                   Bsm + buf * 16384 + h * 8192);
    };

    auto rdA = [&](int buf, int p, bf16x8 (&af)[2][2]) {
        #pragma unroll
        for (int m = 0; m < 2; ++m)
            #pragma unroll
            for (int ks = 0; ks < 2; ++ks) {
                const int r  = wm * 128 + p * 32 + m * 16 + lrow;
                const int cB = (ks * 64 + lgrp * 16) ^ ((r & 7) << 4);
                af[m][ks] = *reinterpret_cast<const bf16x8*>(
                    &Asm[buf * 16384 + ((r * 128 + cB) >> 1)]);
            }
    };
    auto rdB = [&](int buf, bf16x8 (&bfr)[4][2]) {
        #pragma unroll
        for (int n = 0; n < 4; ++n)
            #pragma unroll
            for (int ks = 0; ks < 2; ++ks) {
                const int r  = wn * 64 + n * 16 + lrow;
                const int cB = (ks * 64 + lgrp * 16) ^ ((r & 7) << 4);
                bfr[n][ks] = *reinterpret_cast<const bf16x8*>(
                    &Bsm[buf * 16384 + ((r * 128 + cB) >> 1)]);
            }
    };
    auto mq = [&](int p, bf16x8 (&af)[2][2], bf16x8 (&bfr)[4][2]) {
        __builtin_amdgcn_s_setprio(1);
        #pragma unroll
        for (int ks = 0; ks < 2; ++ks)
            #pragma unroll
            for (int n = 0; n < 4; ++n)
                #pragma unroll
                for (int m = 0; m < 2; ++m)
                    acc[p * 2 + m][n] = __builtin_amdgcn_mfma_f32_16x16x32_bf16(
                        af[m][ks], bfr[n][ks], acc[p * 2 + m][n], 0, 0, 0);
        __builtin_amdgcn_s_setprio(0);
    };

    // ---- prologue: stage tiles 0 (buf0) and 1 (buf1)
    stageA(0, 0, 0); stageA(0, 0, 1);
    stageB(0, 0, 0); stageB(0, 0, 1);
    stageA(1, 1, 0); stageA(1, 1, 1);
    stageB(1, 1, 0); stageB(1, 1, 1);
    asm volatile("s_waitcnt vmcnt(8)" ::: "memory");   // own tile-0 loads done
    BARRIER();                                         // all waves' tile-0 visible

    for (int t = 0; t < NT; t += 2) {
        bf16x8 bfr[4][2], af[2][2];
        // ---- K-tile t (buffers 0) ----
        // ph1 q0 (+ stage A_{t+1} -> Abuf1)
        rdB(0, bfr); rdA(0, 0, af);
        if (t > 0) { stageA(1, t + 1, 0); stageA(1, t + 1, 1); }
        BARRIER(); mq(0, af, bfr); BARRIER();
        // ph2 q1 (+ stage B_{t+2} h0)
        rdA(0, 1, af);
        if (t + 2 < NT) stageB(0, t + 2, 0);
        BARRIER(); mq(1, af, bfr); BARRIER();
        // ph3 q2 (+ stage B_{t+2} h1)
        rdA(0, 2, af);
        if (t + 2 < NT) stageB(0, t + 2, 1);
        BARRIER(); mq(2, af, bfr); BARRIER();
        // ph4 q3; boundary vmcnt ensures A_{t+1},B_{t+1} landed for everyone
        rdA(0, 3, af);
        BARRIER(); mq(3, af, bfr);
        if (t + 2 < NT) { asm volatile("s_waitcnt vmcnt(4)" ::: "memory"); }
        else            { asm volatile("s_waitcnt vmcnt(0)" ::: "memory"); }
        BARRIER();
        // ---- K-tile t+1 (buffers 1) ----
        // ph5 q0 (+ stage A_{t+2} h0 -> Abuf0)
        rdB(1, bfr); rdA(1, 0, af);
        if (t + 2 < NT) stageA(0, t + 2, 0);
        BARRIER(); mq(0, af, bfr); BARRIER();
        // ph6 q1 (+ stage A_{t+2} h1, B_{t+3} h0)
        rdA(1, 1, af);
        if (t + 2 < NT) stageA(0, t + 2, 1);
        if (t + 3 < NT) stageB(1, t + 3, 0);
        BARRIER(); mq(1, af, bfr); BARRIER();
        // ph7 q2 (+ stage B_{t+3} h1)
        rdA(1, 2, af);
        if (t + 3 < NT) stageB(1, t + 3, 1);
        BARRIER(); mq(2, af, bfr); BARRIER();
        // ph8 q3; boundary vmcnt for A_{t+2},B_{t+2}
        rdA(1, 3, af);
        BARRIER(); mq(3, af, bfr);
        if (t + 2 < NT) { asm volatile("s_waitcnt vmcnt(4)" ::: "memory"); }
        BARRIER();
    }

    // ---- epilogue: bias + gelu + bf16 store
    #pragma unroll
    for (int n = 0; n < 4; ++n) {
        const int col = col0 + wn * 64 + n * 16 + lrow;
        const float bv = bias[col];
        #pragma unroll
        for (int mf = 0; mf < 8; ++mf) {
            const int rb = row0 + wm * 128 + mf * 16 + lgrp * 4;
            #pragma unroll
            for (int r = 0; r < 4; ++r) {
                float xv = acc[mf][n][r] + bv;
                if (GELU) xv = 0.5f * xv * (1.f + erff(xv * 0.70710678118654752f));
                C[(size_t)(rb + r) * N + col] = f32_to_bf16(xv);
            }
        }
    }
}

// ---------------- flash attention (unchanged from round 5) ----------------
#define KVP 68
__global__ __launch_bounds__(256) void attn_k(
    const unsigned short* __restrict__ qkv, const int* __restrict__ x,
    float* __restrict__ out)
{
    __shared__ unsigned short KVr[64][KVP];
    __shared__ unsigned short KVt[64 * 64];
    __shared__ unsigned short Ps[4][32][KVP];
    __shared__ float maskf[64];

    int flat = blockIdx.x + 8 * (blockIdx.y + 16 * blockIdx.z);
    flat = (flat & 7) * 64 + (flat >> 3);
    const int qt = flat & 7;
    const int hh = (flat >> 3) & 15;
    const int b  = flat >> 7;

    const int t    = threadIdx.x;
    const int w    = t >> 6;
    const int lane = t & 63;
    const int lrow = lane & 15, lgrp = lane >> 4;

    const unsigned short* qb_  = qkv + ((size_t)b * SEQ) * QKVN + hh * DHEAD;
    const unsigned short* kvb_ = qkv + ((size_t)b * SEQ) * QKVN + EDIM + hh * DHEAD;
    const int* xb = x + b * SEQ;
    const int qrow0 = qt * 128 + w * 32;

    bf16x8 qf[2][2];
    #pragma unroll
    for (int m = 0; m < 2; ++m)
        #pragma unroll
        for (int ks = 0; ks < 2; ++ks)
            qf[m][ks] = *reinterpret_cast<const bf16x8*>(
                qb_ + (size_t)(qrow0 + m * 16 + lrow) * QKVN + ks * 32 + lgrp * 8);

    f32x4 O[2][4];
    float mrun[2][4], lrun[2][4];
    #pragma unroll
    for (int m = 0; m < 2; ++m)
        #pragma unroll
        for (int i = 0; i < 4; ++i) {
            O[m][i] = (f32x4){0.f, 0.f, 0.f, 0.f};
            mrun[m][i] = -3e30f; lrun[m][i] = 0.f;
        }

    for (int kt = 0; kt < SEQ / 64; ++kt) {
        __syncthreads();
        #pragma unroll
        for (int i = 0; i < 4; ++i) {
            const int u2 = t + i * 256;
            const int kr = u2 >> 4, kc = (u2 & 15) * 4;
            const ushort4 v = *reinterpret_cast<const ushort4*>(
                &kvb_[(size_t)(kt * 64 + kr) * QKVN + kc]);
            *reinterpret_cast<ushort4*>(&KVr[kr][kc]) = v;
            const unsigned short comp[4] = {v.x, v.y, v.z, v.w};
            #pragma unroll
            for (int j = 0; j < 4; ++j) {
                const int d = kc + j;
                const int sw = (d ^ (d >> 3)) & 7;
                KVt[(d * 128 + ((kr * 2) ^ (sw << 4))) >> 1] = comp[j];
            }
        }
        if (t < 64) maskf[t] = (xb[kt * 64 + t] != 0) ? 1.f : 0.f;
        __syncthreads();

        f32x4 s[2][4];
        #pragma unroll
        for (int m = 0; m < 2; ++m)
            #pragma unroll
            for (int n = 0; n < 4; ++n) s[m][n] = (f32x4){0.f, 0.f, 0.f, 0.f};
        #pragma unroll
        for (int ks = 0; ks < 2; ++ks)
            #pragma unroll
            for (int n = 0; n < 4; ++n) {
                union { bf16x8 v; ushort4 h[2]; } bb;
                bb.h[0] = *reinterpret_cast<const ushort4*>(
                    &KVr[16 * n + lrow][ks * 32 + lgrp * 8]);
                bb.h[1] = *reinterpret_cast<const ushort4*>(
                    &KVr[16 * n + lrow][ks * 32 + lgrp * 8 + 4]);
                #pragma unroll
                for (int m = 0; m < 2; ++m)
                    s[m][n] = __builtin_amdgcn_mfma_f32_16x16x32_bf16(
                        qf[m][ks], bb.v, s[m][n], 0, 0, 0);
            }

        #pragma unroll
        for (int n = 0; n < 4; ++n) {
            const float flag = maskf[16 * n + lrow];
            #pragma unroll
            for (int m = 0; m < 2; ++m)
                #pragma unroll
                for (int r = 0; r < 4; ++r)
                    s[m][n][r] = (flag != 0.f) ? s[m][n][r] : -1e9f;
        }

        #pragma unroll
        for (int m = 0; m < 2; ++m)
            #pragma unroll
            for (int r = 0; r < 4; ++r) {
                float v = fmaxf(fmaxf(s[m][0][r], s[m][1][r]),
                                fmaxf(s[m][2][r], s[m][3][r]));
                #pragma unroll
                for (int o = 1; o < 16; o <<= 1) v = fmaxf(v, __shfl_xor(v, o));
                const float mn = fmaxf(mrun[m][r], v);
                const float fs = __expf(mrun[m][r] - mn);
                mrun[m][r] = mn;
                lrun[m][r] *= fs;
                #pragma unroll
                for (int df = 0; df < 4; ++df) O[m][df][r] *= fs;
            }

        #pragma unroll
        for (int m = 0; m < 2; ++m) {
            float rsum[4] = {0.f, 0.f, 0.f, 0.f};
            #pragma unroll
            for (int n = 0; n < 4; ++n)
                #pragma unroll
                for (int r = 0; r < 4; ++r) {
                    const float p = __expf(s[m][n][r] - mrun[m][r]);
                    rsum[r] += p;
                    Ps[w][m * 16 + 4 * lgrp + r][16 * n + lrow] = f32_to_bf16(p);
                }
            #pragma unroll
            for (int r = 0; r < 4; ++r) {
                float v = rsum[r];
                #pragma unroll
                for (int o = 1; o < 16; o <<= 1) v += __shfl_xor(v, o);
                lrun[m][r] += v;
            }
        }

        #pragma unroll
        for (int ks = 0; ks < 2; ++ks) {
            bf16x8 paf[2];
            #pragma unroll
            for (int m = 0; m < 2; ++m) {
                union { bf16x8 v; ushort4 h[2]; } pp;
                pp.h[0] = *reinterpret_cast<const ushort4*>(
                    &Ps[w][m * 16 + lrow][ks * 32 + lgrp * 8]);
                pp.h[1] = *reinterpret_cast<const ushort4*>(
                    &Ps[w][m * 16 + lrow][ks * 32 + lgrp * 8 + 4]);
                paf[m] = pp.v;
            }
            #pragma unroll
            for (int df = 0; df < 4; ++df) {
                const int d  = 16 * df + lrow;
                const int sw = (d ^ (d >> 3)) & 7;
                const bf16x8 bvf = *reinterpret_cast<const bf16x8*>(
                    &KVt[(d * 128 + ((ks * 64 + lgrp * 16) ^ (sw << 4))) >> 1]);
                #pragma unroll
                for (int m = 0; m < 2; ++m)
                    O[m][df] = __builtin_amdgcn_mfma_f32_16x16x32_bf16(
                        paf[m], bvf, O[m][df], 0, 0, 0);
            }
        }
    }

    #pragma unroll
    for (int m = 0; m < 2; ++m)
        #pragma unroll
        for (int r = 0; r < 4; ++r) {
            const float inv = 1.f / lrun[m][r];
            const int row = qrow0 + m * 16 + 4 * lgrp + r;
            float* po = out + ((size_t)b * SEQ + row) * EDIM + hh * DHEAD;
            #pragma unroll
            for (int df = 0; df < 4; ++df)
                po[16 * df + lrow] = O[m][df][r] * inv;
        }
}

// ---------------- driver ----------------
extern "C" void kernel_launch(void* const* d_in, const int* in_sizes, int n_in,
                              void* d_out, int out_size, void* d_ws, size_t ws_size,
                              hipStream_t stream)
{
    (void)in_sizes; (void)n_in; (void)out_size; (void)ws_size;

    const int*   x     = (const int*)  d_in[0];
    const float* wte   = (const float*)d_in[1];
    const float* wpe   = (const float*)d_in[2];
    const float* Wq    = (const float*)d_in[3];
    const float* bq    = (const float*)d_in[4];
    const float* Wkv   = (const float*)d_in[5];
    const float* bkv   = (const float*)d_in[6];
    const float* Wfc   = (const float*)d_in[7];
    const float* bfc   = (const float*)d_in[8];
    const float* Wproj = (const float*)d_in[9];
    const float* bproj = (const float*)d_in[10];
    const float* ln1g  = (const float*)d_in[11];
    const float* ln1b  = (const float*)d_in[12];
    const float* ln2g  = (const float*)d_in[13];
    const float* ln2b  = (const float*)d_in[14];
    const float* lnfg  = (const float*)d_in[15];
    const float* lnfb  = (const float*)d_in[16];

    const size_t MB = 1024 * 1024;
    char* W = (char*)d_ws;
    float*          h     = (float*)(W + 0 * MB);            // 16 MB
    float*          att   = (float*)(W + 16 * MB);           // 16 MB (reused as mb2)
    float*          mb    = (float*)(W + 32 * MB);           // 16 MB
    unsigned short* hb    = (unsigned short*)(W + 48 * MB);  // 8 MB
    unsigned short* qkv   = (unsigned short*)(W + 56 * MB);  // 16 MB
    unsigned short* ub    = (unsigned short*)(W + 72 * MB);  // 8 MB
    unsigned short* tb    = (unsigned short*)(W + 80 * MB);  // 32 MB
    float*          bqkv  = (float*)(W + 112 * MB);          // 96 KB
    unsigned short* wqkvT = (unsigned short*)(W + 113 * MB); // 48 MB
    unsigned short* wfcT  = (unsigned short*)(W + 161 * MB); // 96 MB
    unsigned short* wpjT  = (unsigned short*)(W + 257 * MB); // 96 MB (end 353 MB)

    // ---- one-time prep
    bias_concat_k<<<NLAYER, 256, 0, stream>>>(bq, bkv, bqkv);
    transpose_bf16_k<<<dim3(32, 32, NLAYER), 256, 0, stream>>>(
        Wq, wqkvT, EDIM, EDIM, (size_t)EDIM * EDIM, (size_t)QKVN * EDIM);
    transpose_bf16_k<<<dim3(32, 32, NLAYER), 256, 0, stream>>>(
        Wkv, wqkvT + (size_t)EDIM * EDIM, EDIM, EDIM,
        (size_t)EDIM * EDIM, (size_t)QKVN * EDIM);
    transpose_bf16_k<<<dim3(128, 32, NLAYER), 256, 0, stream>>>(
        Wfc, wfcT, EDIM, 4 * EDIM, (size_t)4 * EDIM * EDIM, (size_t)4 * EDIM * EDIM);
    transpose_bf16_k<<<dim3(32, 128, NLAYER), 256, 0, stream>>>(
        Wproj, wpjT, 4 * EDIM, EDIM, (size_t)4 * EDIM * EDIM, (size_t)4 * EDIM * EDIM);

    embed_k<<<NTOK, 256, 0, stream>>>(x, wte, wpe, h, hb);

    for (int l = 0; l < NLAYER; ++l) {
        gemm_bt_k<0, 1><<<dim3(QKVN / 128, NTOK / 128), 256, 0, stream>>>(
            hb, wqkvT + (size_t)l * QKVN * EDIM, bqkv + (size_t)l * QKVN,
            qkv, nullptr, NTOK, QKVN, EDIM);

        attn_k<<<dim3(SEQ / 128, NHEAD, 4), 256, 0, stream>>>(qkv, x, att);

        add_ln_k<2, 0, 1><<<NTOK, 256, 0, stream>>>(
            h, att, nullptr, ln1g + l * EDIM, ln1b + l * EDIM, nullptr, ub);

        // FC: 8-phase 256^2 kernel (256 blocks = 1/CU)
        gemm256_k<1><<<dim3((NTOK / 256) * (4 * EDIM / 256)), 512, 0, stream>>>(
            ub, wfcT + (size_t)l * 4 * EDIM * EDIM, bfc + (size_t)l * 4 * EDIM,
            tb, NTOK, 4 * EDIM, EDIM);

        // proj split-K=2: z=0 -> mb (with bias), z=1 -> att buffer (partial)
        gemm_bt_k<0, 0><<<dim3(EDIM / 128, NTOK / 128, 2), 256, 0, stream>>>(
            tb, wpjT + (size_t)l * 4 * EDIM * EDIM, bproj + (size_t)l * EDIM,
            mb, att, NTOK, EDIM, 4 * EDIM);

        add_ln_k<3, 1, 1><<<NTOK, 256, 0, stream>>>(
            mb, att, h, ln2g + l * EDIM, ln2b + l * EDIM, h, hb);
    }

    add_ln_k<1, 1, 0><<<NTOK, 256, 0, stream>>>(
        h, nullptr, nullptr, lnfg, lnfb, (float*)d_out, nullptr);
}

// Round 7
// 2690.676 us; speedup vs baseline: 1.3894x; 1.0971x over previous
//
#include <hip/hip_runtime.h>

#define SEQ    1024
#define EDIM   1024
#define NHEAD  16
#define DHEAD  64
#define NLAYER 12
#define NTOK   4096   // B*S
#define QKVN   2048   // fused q|kv output width

typedef float f32x4  __attribute__((ext_vector_type(4)));
typedef short bf16x8 __attribute__((ext_vector_type(8)));

__device__ __forceinline__ unsigned short f32_to_bf16(float f) {
    union { float f; unsigned u; } v; v.f = f;
    return (unsigned short)((v.u + 0x7fffu + ((v.u >> 16) & 1u)) >> 16);
}

__device__ __forceinline__ void gload_lds16(const unsigned short* g, unsigned short* l) {
    __builtin_amdgcn_global_load_lds((const __attribute__((address_space(1))) void*)g,
                                     (__attribute__((address_space(3))) void*)l, 16, 0, 0);
}

#define BARRIER() do { __builtin_amdgcn_s_barrier(); asm volatile("" ::: "memory"); } while (0)

// ---------------- weight prep: W [K][N] f32 -> WT [N][K] bf16, all layers ----------------
__global__ __launch_bounds__(256) void transpose_bf16_k(
    const float* __restrict__ W, unsigned short* __restrict__ WT,
    int K, int N, size_t wStride, size_t wtStride)
{
    __shared__ float tile[32][33];
    const int l = blockIdx.z;
    W  += (size_t)l * wStride;
    WT += (size_t)l * wtStride;
    const int n0 = blockIdx.x * 32, k0 = blockIdx.y * 32;
    const int t = threadIdx.x;
    const int r = t >> 3, c4 = (t & 7) * 4;
    const float4 v = *reinterpret_cast<const float4*>(&W[(size_t)(k0 + r) * N + n0 + c4]);
    tile[r][c4 + 0] = v.x; tile[r][c4 + 1] = v.y;
    tile[r][c4 + 2] = v.z; tile[r][c4 + 3] = v.w;
    __syncthreads();
    ushort4 o;
    o.x = f32_to_bf16(tile[c4 + 0][r]);
    o.y = f32_to_bf16(tile[c4 + 1][r]);
    o.z = f32_to_bf16(tile[c4 + 2][r]);
    o.w = f32_to_bf16(tile[c4 + 3][r]);
    *reinterpret_cast<ushort4*>(&WT[(size_t)(n0 + r) * K + k0 + c4]) = o;
}

// ---------------- bias concat ----------------
__global__ __launch_bounds__(256) void bias_concat_k(
    const float* __restrict__ bq, const float* __restrict__ bkv,
    float* __restrict__ bqkv)
{
    const int l = blockIdx.x, t = threadIdx.x;
    #pragma unroll
    for (int i = 0; i < 4; ++i) {
        const int c = t + i * 256;
        bqkv[(size_t)l * QKVN + c]        = bq[(size_t)l * EDIM + c];
        bqkv[(size_t)l * QKVN + EDIM + c] = bkv[(size_t)l * EDIM + c];
    }
}

// ---------------- embedding ----------------
__global__ __launch_bounds__(256) void embed_k(
    const int* __restrict__ x, const float* __restrict__ wte,
    const float* __restrict__ wpe, float* __restrict__ h,
    unsigned short* __restrict__ hb)
{
    const int bs  = blockIdx.x;
    const int s   = bs & (SEQ - 1);
    const int tok = x[bs];
    const int c   = threadIdx.x * 4;
    float4 a = *reinterpret_cast<const float4*>(&wte[(size_t)tok * EDIM + c]);
    const float4 p = *reinterpret_cast<const float4*>(&wpe[(size_t)s * EDIM + c]);
    a.x += p.x; a.y += p.y; a.z += p.z; a.w += p.w;
    *reinterpret_cast<float4*>(&h[(size_t)bs * EDIM + c]) = a;
    ushort4 o;
    o.x = f32_to_bf16(a.x); o.y = f32_to_bf16(a.y);
    o.z = f32_to_bf16(a.z); o.w = f32_to_bf16(a.w);
    *reinterpret_cast<ushort4*>(&hb[(size_t)bs * EDIM + c]) = o;
}

// ---------------- layernorm(sum of up to 5 inputs) ----------------
template<int NADD, int WF32, int WBF16>
__global__ __launch_bounds__(256) void add_ln_k(
    const float* __restrict__ x1, const float* __restrict__ x2,
    const float* __restrict__ x3, const float* __restrict__ x4,
    const float* __restrict__ x5, const float* __restrict__ g,
    const float* __restrict__ b, float* __restrict__ outf,
    unsigned short* __restrict__ outb)
{
    const int row = blockIdx.x;
    const int t   = threadIdx.x;
    const int c   = t * 4;
    const size_t base = (size_t)row * EDIM + c;
    float4 a = *reinterpret_cast<const float4*>(x1 + base);
    if (NADD >= 2) {
        const float4 v = *reinterpret_cast<const float4*>(x2 + base);
        a.x += v.x; a.y += v.y; a.z += v.z; a.w += v.w;
    }
    if (NADD >= 3) {
        const float4 v = *reinterpret_cast<const float4*>(x3 + base);
        a.x += v.x; a.y += v.y; a.z += v.z; a.w += v.w;
    }
    if (NADD >= 4) {
        const float4 v = *reinterpret_cast<const float4*>(x4 + base);
        a.x += v.x; a.y += v.y; a.z += v.z; a.w += v.w;
    }
    if (NADD >= 5) {
        const float4 v = *reinterpret_cast<const float4*>(x5 + base);
        a.x += v.x; a.y += v.y; a.z += v.z; a.w += v.w;
    }
    float s  = a.x + a.y + a.z + a.w;
    float ss = a.x * a.x + a.y * a.y + a.z * a.z + a.w * a.w;
    #pragma unroll
    for (int o = 32; o > 0; o >>= 1) {
        s  += __shfl_down(s, o);
        ss += __shfl_down(ss, o);
    }
    __shared__ float rs[4], rss[4];
    const int lane = t & 63, wv = t >> 6;
    if (lane == 0) { rs[wv] = s; rss[wv] = ss; }
    __syncthreads();
    s  = rs[0] + rs[1] + rs[2] + rs[3];
    ss = rss[0] + rss[1] + rss[2] + rss[3];
    const float mean = s * (1.f / EDIM);
    const float var  = ss * (1.f / EDIM) - mean * mean;
    const float inv  = rsqrtf(var + 1e-5f);
    const float4 gv = *reinterpret_cast<const float4*>(g + c);
    const float4 bv = *reinterpret_cast<const float4*>(b + c);
    float4 y;
    y.x = (a.x - mean) * inv * gv.x + bv.x;
    y.y = (a.y - mean) * inv * gv.y + bv.y;
    y.z = (a.z - mean) * inv * gv.z + bv.z;
    y.w = (a.w - mean) * inv * gv.w + bv.w;
    if (WF32) *reinterpret_cast<float4*>(outf + base) = y;
    if (WBF16) {
        ushort4 o;
        o.x = f32_to_bf16(y.x); o.y = f32_to_bf16(y.y);
        o.z = f32_to_bf16(y.z); o.w = f32_to_bf16(y.w);
        *reinterpret_cast<ushort4*>(outb + base) = o;
    }
}

// ---------------- GEMM m97 (128^2, used for qkv + proj fallback) ----------------
template<int GELU, int OUTBF16>
__global__ __launch_bounds__(256) void gemm_bt_k(
    const unsigned short* __restrict__ A,
    const unsigned short* __restrict__ BT,
    const float* __restrict__ bias, void* __restrict__ Cout,
    void* __restrict__ Cout2, int M, int N, int K)
{
    __shared__ unsigned short As[128 * 32];
    __shared__ unsigned short Bs[128 * 32];

    const int t    = threadIdx.x;
    const int lane = t & 63;
    const int wave = t >> 6;
    const int wr   = wave >> 1, wc = wave & 1;
    const int lrow = lane & 15, lgrp = lane >> 4;

    const int nbx = gridDim.x;
    int flat = blockIdx.y * nbx + blockIdx.x;
    const int nwg = nbx * gridDim.y;
    flat = (flat & 7) * (nwg >> 3) + (flat >> 3);
    const int row0 = (flat / nbx) * 128, col0 = (flat % nbx) * 128;

    const int kspan = K / gridDim.z;
    const int koff  = blockIdx.z * kspan;

    const int srow  = lane >> 2;
    const int skoff = (lane & 3) * 8;
    const unsigned short* aP0 = A  + (size_t)(row0 + 32 * wave + srow) * K + skoff;
    const unsigned short* aP1 = aP0 + (size_t)16 * K;
    const unsigned short* bP0 = BT + (size_t)(col0 + 32 * wave + srow) * K + skoff;
    const unsigned short* bP1 = bP0 + (size_t)16 * K;
    unsigned short* aL0 = As + wave * 1024;
    unsigned short* aL1 = As + wave * 1024 + 512;
    unsigned short* bL0 = Bs + wave * 1024;
    unsigned short* bL1 = Bs + wave * 1024 + 512;

    f32x4 acc[4][4];
    #pragma unroll
    for (int i = 0; i < 4; ++i)
        #pragma unroll
        for (int j = 0; j < 4; ++j)
            acc[i][j] = (f32x4){0.f, 0.f, 0.f, 0.f};

    for (int k0 = koff; k0 < koff + kspan; k0 += 32) {
        gload_lds16(aP0 + k0, aL0);
        gload_lds16(aP1 + k0, aL1);
        gload_lds16(bP0 + k0, bL0);
        gload_lds16(bP1 + k0, bL1);
        __syncthreads();

        bf16x8 af[4], bf[4];
        #pragma unroll
        for (int m = 0; m < 4; ++m)
            af[m] = *reinterpret_cast<const bf16x8*>(
                &As[(wr * 64 + m * 16 + lrow) * 32 + lgrp * 8]);
        #pragma unroll
        for (int n = 0; n < 4; ++n)
            bf[n] = *reinterpret_cast<const bf16x8*>(
                &Bs[(wc * 64 + n * 16 + lrow) * 32 + lgrp * 8]);

        #pragma unroll
        for (int n = 0; n < 4; ++n)
            #pragma unroll
            for (int m = 0; m < 4; ++m)
                acc[m][n] = __builtin_amdgcn_mfma_f32_16x16x32_bf16(
                    af[m], bf[n], acc[m][n], 0, 0, 0);
        __syncthreads();
    }

    const int z = blockIdx.z;
    #pragma unroll
    for (int n = 0; n < 4; ++n) {
        const int col = col0 + wc * 64 + n * 16 + lrow;
        const float bv = (z == 0) ? bias[col] : 0.f;
        #pragma unroll
        for (int m = 0; m < 4; ++m) {
            const int rb = row0 + wr * 64 + m * 16 + lgrp * 4;
            #pragma unroll
            for (int r = 0; r < 4; ++r) {
                float xv = acc[m][n][r] + bv;
                if (GELU) xv = 0.5f * xv * (1.f + erff(xv * 0.70710678118654752f));
                if (OUTBF16) {
                    ((unsigned short*)Cout)[(size_t)(rb + r) * N + col] = f32_to_bf16(xv);
                } else {
                    float* dst = (z == 0) ? (float*)Cout : (float*)Cout2;
                    dst[(size_t)(rb + r) * N + col] = xv;
                }
            }
        }
    }
}

// ---------------- GEMM 256^2 8-phase (T2+T3+T4+T5); OUT: 0=bf16, 1=f32 multi-z ----------------
template<int GELU, int OUT>
__global__ __launch_bounds__(512) void gemm256_k(
    const unsigned short* __restrict__ A,
    const unsigned short* __restrict__ BT,
    const float* __restrict__ bias, unsigned short* __restrict__ C,
    float* __restrict__ P0, float* __restrict__ P1,
    float* __restrict__ P2, float* __restrict__ P3,
    int M, int N, int K)
{
    __shared__ unsigned short sh[65536];          // A: [0,32768) B: [32768,65536)
    unsigned short* Asm = sh;
    unsigned short* Bsm = sh + 32768;

    const int tid  = threadIdx.x;
    const int lane = tid & 63;
    const int wave = tid >> 6;
    const int wm   = wave >> 2;
    const int wn   = wave & 3;
    const int lrow = lane & 15, lgrp = lane >> 4;

    const int ntc = N >> 8;
    const int nwg = gridDim.x;
    int flat = (blockIdx.x & 7) * (nwg >> 3) + (blockIdx.x >> 3);
    const int row0 = (flat / ntc) * 256;
    const int col0 = (flat % ntc) * 256;

    const int kspan = K / gridDim.y;
    const int koff  = blockIdx.y * kspan;
    const int NT    = kspan >> 6;

    f32x4 acc[8][4];
    #pragma unroll
    for (int i = 0; i < 8; ++i)
        #pragma unroll
        for (int j = 0; j < 4; ++j)
            acc[i][j] = (f32x4){0.f, 0.f, 0.f, 0.f};

    auto stage_half = [&](const unsigned short* g, unsigned short* l) {
        #pragma unroll
        for (int c = 0; c < 2; ++c) {
            const int d = (tid + c * 512) * 16;
            const int L = d ^ (((d >> 7) & 7) << 4);
            gload_lds16(g + (size_t)(L >> 7) * K + ((L & 127) >> 1), l + (d >> 1));
        }
    };
    auto stageA = [&](int buf, int kt, int h) {
        stage_half(A + (size_t)(row0 + h * 128) * K + koff + kt * 64,
                   Asm + buf * 16384 + h * 8192);
    };
    auto stageB = [&](int buf, int kt, int h) {
        stage_half(BT + (size_t)(col0 + h * 128) * K + koff + kt * 64,
                   Bsm + buf * 16384 + h * 8192);
    };

    auto rdA = [&](int buf, int p, bf16x8 (&af)[2][2]) {
        #pragma unroll
        for (int m = 0; m < 2; ++m)
            #pragma unroll
            for (int ks = 0; ks < 2; ++ks) {
                const int r  = wm * 128 + p * 32 + m * 16 + lrow;
                const int cB = (ks * 64 + lgrp * 16) ^ ((r & 7) << 4);
                af[m][ks] = *reinterpret_cast<const bf16x8*>(
                    &Asm[buf * 16384 + ((r * 128 + cB) >> 1)]);
            }
    };
    auto rdB = [&](int buf, bf16x8 (&bfr)[4][2]) {
        #pragma unroll
        for (int n = 0; n < 4; ++n)
            #pragma unroll
            for (int ks = 0; ks < 2; ++ks) {
                const int r  = wn * 64 + n * 16 + lrow;
                const int cB = (ks * 64 + lgrp * 16) ^ ((r & 7) << 4);
                bfr[n][ks] = *reinterpret_cast<const bf16x8*>(
                    &Bsm[buf * 16384 + ((r * 128 + cB) >> 1)]);
            }
    };
    auto mq = [&](int p, bf16x8 (&af)[2][2], bf16x8 (&bfr)[4][2]) {
        __builtin_amdgcn_s_setprio(1);
        #pragma unroll
        for (int ks = 0; ks < 2; ++ks)
            #pragma unroll
            for (int n = 0; n < 4; ++n)
                #pragma unroll
                for (int m = 0; m < 2; ++m)
                    acc[p * 2 + m][n] = __builtin_amdgcn_mfma_f32_16x16x32_bf16(
                        af[m][ks], bfr[n][ks], acc[p * 2 + m][n], 0, 0, 0);
        __builtin_amdgcn_s_setprio(0);
    };

    stageA(0, 0, 0); stageA(0, 0, 1);
    stageB(0, 0, 0); stageB(0, 0, 1);
    stageA(1, 1, 0); stageA(1, 1, 1);
    stageB(1, 1, 0); stageB(1, 1, 1);
    asm volatile("s_waitcnt vmcnt(8)" ::: "memory");
    BARRIER();

    for (int t = 0; t < NT; t += 2) {
        bf16x8 bfr[4][2], af[2][2];
        // ---- K-tile t (buf 0)
        rdB(0, bfr); rdA(0, 0, af);
        if (t > 0) { stageA(1, t + 1, 0); stageA(1, t + 1, 1); }
        BARRIER(); mq(0, af, bfr); BARRIER();
        rdA(0, 1, af);
        if (t + 2 < NT) stageB(0, t + 2, 0);
        BARRIER(); mq(1, af, bfr); BARRIER();
        rdA(0, 2, af);
        if (t + 2 < NT) stageB(0, t + 2, 1);
        BARRIER(); mq(2, af, bfr); BARRIER();
        rdA(0, 3, af);
        BARRIER(); mq(3, af, bfr);
        if (t + 2 < NT) { asm volatile("s_waitcnt vmcnt(4)" ::: "memory"); }
        else            { asm volatile("s_waitcnt vmcnt(0)" ::: "memory"); }
        BARRIER();
        // ---- K-tile t+1 (buf 1)
        rdB(1, bfr); rdA(1, 0, af);
        if (t + 2 < NT) stageA(0, t + 2, 0);
        BARRIER(); mq(0, af, bfr); BARRIER();
        rdA(1, 1, af);
        if (t + 2 < NT) stageA(0, t + 2, 1);
        if (t + 3 < NT) stageB(1, t + 3, 0);
        BARRIER(); mq(1, af, bfr); BARRIER();
        rdA(1, 2, af);
        if (t + 3 < NT) stageB(1, t + 3, 1);
        BARRIER(); mq(2, af, bfr); BARRIER();
        rdA(1, 3, af);
        BARRIER(); mq(3, af, bfr);
        if (t + 2 < NT) { asm volatile("s_waitcnt vmcnt(4)" ::: "memory"); }
        BARRIER();
    }

    const int z = blockIdx.y;
    #pragma unroll
    for (int n = 0; n < 4; ++n) {
        const int col = col0 + wn * 64 + n * 16 + lrow;
        const float bv = (z == 0) ? bias[col] : 0.f;
        #pragma unroll
        for (int mf = 0; mf < 8; ++mf) {
            const int rb = row0 + wm * 128 + mf * 16 + lgrp * 4;
            #pragma unroll
            for (int r = 0; r < 4; ++r) {
                float xv = acc[mf][n][r] + bv;
                if (GELU) xv = 0.5f * xv * (1.f + erff(xv * 0.70710678118654752f));
                if (OUT == 0) {
                    C[(size_t)(rb + r) * N + col] = f32_to_bf16(xv);
                } else {
                    float* dst = (z == 0) ? P0 : (z == 1) ? P1 : (z == 2) ? P2 : P3;
                    dst[(size_t)(rb + r) * N + col] = xv;
                }
            }
        }
    }
}

// ---------------- flash attention + T14 async-STAGE split ----------------
#define KVP 68
__global__ __launch_bounds__(256) void attn_k(
    const unsigned short* __restrict__ qkv, const int* __restrict__ x,
    float* __restrict__ out)
{
    __shared__ unsigned short KVr[64][KVP];
    __shared__ unsigned short KVt[64 * 64];
    __shared__ unsigned short Ps[4][32][KVP];
    __shared__ float maskf[64];

    int flat = blockIdx.x + 8 * (blockIdx.y + 16 * blockIdx.z);
    flat = (flat & 7) * 64 + (flat >> 3);
    const int qt = flat & 7;
    const int hh = (flat >> 3) & 15;
    const int b  = flat >> 7;

    const int t    = threadIdx.x;
    const int w    = t >> 6;
    const int lane = t & 63;
    const int lrow = lane & 15, lgrp = lane >> 4;

    const unsigned short* qb_  = qkv + ((size_t)b * SEQ) * QKVN + hh * DHEAD;
    const unsigned short* kvb_ = qkv + ((size_t)b * SEQ) * QKVN + EDIM + hh * DHEAD;
    const int* xb = x + b * SEQ;
    const int qrow0 = qt * 128 + w * 32;

    bf16x8 qf[2][2];
    #pragma unroll
    for (int m = 0; m < 2; ++m)
        #pragma unroll
        for (int ks = 0; ks < 2; ++ks)
            qf[m][ks] = *reinterpret_cast<const bf16x8*>(
                qb_ + (size_t)(qrow0 + m * 16 + lrow) * QKVN + ks * 32 + lgrp * 8);

    f32x4 O[2][4];
    float mrun[2][4], lrun[2][4];
    #pragma unroll
    for (int m = 0; m < 2; ++m)
        #pragma unroll
        for (int i = 0; i < 4; ++i) {
            O[m][i] = (f32x4){0.f, 0.f, 0.f, 0.f};
            mrun[m][i] = -3e30f; lrun[m][i] = 0.f;
        }

    const int NKT = SEQ / 64;
    ushort4 kvreg[4];
    int xv = 0;

    // T14: issue tile-kt loads into registers; LDS write happens next iteration
    auto issueKV = [&](int kt) {
        #pragma unroll
        for (int i = 0; i < 4; ++i) {
            const int u2 = t + i * 256;
            const int kr = u2 >> 4, kc = (u2 & 15) * 4;
            kvreg[i] = *reinterpret_cast<const ushort4*>(
                &kvb_[(size_t)(kt * 64 + kr) * QKVN + kc]);
        }
        if (t < 64) xv = xb[kt * 64 + t];
    };
    issueKV(0);

    for (int kt = 0; kt < NKT; ++kt) {
        __syncthreads();   // all waves done reading previous tile's LDS
        #pragma unroll
        for (int i = 0; i < 4; ++i) {
            const int u2 = t + i * 256;
            const int kr = u2 >> 4, kc = (u2 & 15) * 4;
            *reinterpret_cast<ushort4*>(&KVr[kr][kc]) = kvreg[i];
            const unsigned short comp[4] = {kvreg[i].x, kvreg[i].y, kvreg[i].z, kvreg[i].w};
            #pragma unroll
            for (int j = 0; j < 4; ++j) {
                const int d = kc + j;
                const int sw = (d ^ (d >> 3)) & 7;
                KVt[(d * 128 + ((kr * 2) ^ (sw << 4))) >> 1] = comp[j];
            }
        }
        if (t < 64) maskf[t] = (xv != 0) ? 1.f : 0.f;
        if (kt + 1 < NKT) issueKV(kt + 1);   // loads fly during compute below
        __syncthreads();

        f32x4 s[2][4];
        #pragma unroll
        for (int m = 0; m < 2; ++m)
            #pragma unroll
            for (int n = 0; n < 4; ++n) s[m][n] = (f32x4){0.f, 0.f, 0.f, 0.f};
        #pragma unroll
        for (int ks = 0; ks < 2; ++ks)
            #pragma unroll
            for (int n = 0; n < 4; ++n) {
                union { bf16x8 v; ushort4 h[2]; } bb;
                bb.h[0] = *reinterpret_cast<const ushort4*>(
                    &KVr[16 * n + lrow][ks * 32 + lgrp * 8]);
                bb.h[1] = *reinterpret_cast<const ushort4*>(
                    &KVr[16 * n + lrow][ks * 32 + lgrp * 8 + 4]);
                #pragma unroll
                for (int m = 0; m < 2; ++m)
                    s[m][n] = __builtin_amdgcn_mfma_f32_16x16x32_bf16(
                        qf[m][ks], bb.v, s[m][n], 0, 0, 0);
            }

        #pragma unroll
        for (int n = 0; n < 4; ++n) {
            const float flag = maskf[16 * n + lrow];
            #pragma unroll
            for (int m = 0; m < 2; ++m)
                #pragma unroll
                for (int r = 0; r < 4; ++r)
                    s[m][n][r] = (flag != 0.f) ? s[m][n][r] : -1e9f;
        }

        #pragma unroll
        for (int m = 0; m < 2; ++m)
            #pragma unroll
            for (int r = 0; r < 4; ++r) {
                float v = fmaxf(fmaxf(s[m][0][r], s[m][1][r]),
                                fmaxf(s[m][2][r], s[m][3][r]));
                #pragma unroll
                for (int o = 1; o < 16; o <<= 1) v = fmaxf(v, __shfl_xor(v, o));
                const float mn = fmaxf(mrun[m][r], v);
                const float fs = __expf(mrun[m][r] - mn);
                mrun[m][r] = mn;
                lrun[m][r] *= fs;
                #pragma unroll
                for (int df = 0; df < 4; ++df) O[m][df][r] *= fs;
            }

        #pragma unroll
        for (int m = 0; m < 2; ++m) {
            float rsum[4] = {0.f, 0.f, 0.f, 0.f};
            #pragma unroll
            for (int n = 0; n < 4; ++n)
                #pragma unroll
                for (int r = 0; r < 4; ++r) {
                    const float p = __expf(s[m][n][r] - mrun[m][r]);
                    rsum[r] += p;
                    Ps[w][m * 16 + 4 * lgrp + r][16 * n + lrow] = f32_to_bf16(p);
                }
            #pragma unroll
            for (int r = 0; r < 4; ++r) {
                float v = rsum[r];
                #pragma unroll
                for (int o = 1; o < 16; o <<= 1) v += __shfl_xor(v, o);
                lrun[m][r] += v;
            }
        }

        #pragma unroll
        for (int ks = 0; ks < 2; ++ks) {
            bf16x8 paf[2];
            #pragma unroll
            for (int m = 0; m < 2; ++m) {
                union { bf16x8 v; ushort4 h[2]; } pp;
                pp.h[0] = *reinterpret_cast<const ushort4*>(
                    &Ps[w][m * 16 + lrow][ks * 32 + lgrp * 8]);
                pp.h[1] = *reinterpret_cast<const ushort4*>(
                    &Ps[w][m * 16 + lrow][ks * 32 + lgrp * 8 + 4]);
                paf[m] = pp.v;
            }
            #pragma unroll
            for (int df = 0; df < 4; ++df) {
                const int d  = 16 * df + lrow;
                const int sw = (d ^ (d >> 3)) & 7;
                const bf16x8 bvf = *reinterpret_cast<const bf16x8*>(
                    &KVt[(d * 128 + ((ks * 64 + lgrp * 16) ^ (sw << 4))) >> 1]);
                #pragma unroll
                for (int m = 0; m < 2; ++m)
                    O[m][df] = __builtin_amdgcn_mfma_f32_16x16x32_bf16(
                        paf[m], bvf, O[m][df], 0, 0, 0);
            }
        }
    }

    #pragma unroll
    for (int m = 0; m < 2; ++m)
        #pragma unroll
        for (int r = 0; r < 4; ++r) {
            const float inv = 1.f / lrun[m][r];
            const int row = qrow0 + m * 16 + 4 * lgrp + r;
            float* po = out + ((size_t)b * SEQ + row) * EDIM + hh * DHEAD;
            #pragma unroll
            for (int df = 0; df < 4; ++df)
                po[16 * df + lrow] = O[m][df][r] * inv;
        }
}

// ---------------- driver ----------------
extern "C" void kernel_launch(void* const* d_in, const int* in_sizes, int n_in,
                              void* d_out, int out_size, void* d_ws, size_t ws_size,
                              hipStream_t stream)
{
    (void)in_sizes; (void)n_in; (void)out_size;

    const int*   x     = (const int*)  d_in[0];
    const float* wte   = (const float*)d_in[1];
    const float* wpe   = (const float*)d_in[2];
    const float* Wq    = (const float*)d_in[3];
    const float* bq    = (const float*)d_in[4];
    const float* Wkv   = (const float*)d_in[5];
    const float* bkv   = (const float*)d_in[6];
    const float* Wfc   = (const float*)d_in[7];
    const float* bfc   = (const float*)d_in[8];
    const float* Wproj = (const float*)d_in[9];
    const float* bproj = (const float*)d_in[10];
    const float* ln1g  = (const float*)d_in[11];
    const float* ln1b  = (const float*)d_in[12];
    const float* ln2g  = (const float*)d_in[13];
    const float* ln2b  = (const float*)d_in[14];
    const float* lnfg  = (const float*)d_in[15];
    const float* lnfb  = (const float*)d_in[16];

    const size_t MB = 1024 * 1024;
    char* W = (char*)d_ws;
    float*          h     = (float*)(W + 0 * MB);            // 16 MB
    float*          att   = (float*)(W + 16 * MB);           // 16 MB (also proj partial z1)
    float*          mb    = (float*)(W + 32 * MB);           // 16 MB (proj z0)
    unsigned short* hb    = (unsigned short*)(W + 48 * MB);  // 8 MB
    unsigned short* qkv   = (unsigned short*)(W + 56 * MB);  // 16 MB (dead during proj -> z2)
    unsigned short* ub    = (unsigned short*)(W + 72 * MB);  // 8 MB
    unsigned short* tb    = (unsigned short*)(W + 80 * MB);  // 32 MB
    float*          bqkv  = (float*)(W + 112 * MB);          // 96 KB
    unsigned short* wqkvT = (unsigned short*)(W + 113 * MB); // 48 MB
    unsigned short* wfcT  = (unsigned short*)(W + 161 * MB); // 96 MB
    unsigned short* wpjT  = (unsigned short*)(W + 257 * MB); // 96 MB (end 353 MB)
    float*          p2f   = (float*)(W + 56 * MB);           // alias of qkv region
    float*          p3f   = (float*)(W + 353 * MB);          // 16 MB (guarded)

    const bool split4 = ws_size >= (size_t)369 * MB;

    // ---- one-time prep
    bias_concat_k<<<NLAYER, 256, 0, stream>>>(bq, bkv, bqkv);
    transpose_bf16_k<<<dim3(32, 32, NLAYER), 256, 0, stream>>>(
        Wq, wqkvT, EDIM, EDIM, (size_t)EDIM * EDIM, (size_t)QKVN * EDIM);
    transpose_bf16_k<<<dim3(32, 32, NLAYER), 256, 0, stream>>>(
        Wkv, wqkvT + (size_t)EDIM * EDIM, EDIM, EDIM,
        (size_t)EDIM * EDIM, (size_t)QKVN * EDIM);
    transpose_bf16_k<<<dim3(128, 32, NLAYER), 256, 0, stream>>>(
        Wfc, wfcT, EDIM, 4 * EDIM, (size_t)4 * EDIM * EDIM, (size_t)4 * EDIM * EDIM);
    transpose_bf16_k<<<dim3(32, 128, NLAYER), 256, 0, stream>>>(
        Wproj, wpjT, 4 * EDIM, EDIM, (size_t)4 * EDIM * EDIM, (size_t)4 * EDIM * EDIM);

    embed_k<<<NTOK, 256, 0, stream>>>(x, wte, wpe, h, hb);

    for (int l = 0; l < NLAYER; ++l) {
        gemm_bt_k<0, 1><<<dim3(QKVN / 128, NTOK / 128), 256, 0, stream>>>(
            hb, wqkvT + (size_t)l * QKVN * EDIM, bqkv + (size_t)l * QKVN,
            qkv, nullptr, NTOK, QKVN, EDIM);

        attn_k<<<dim3(SEQ / 128, NHEAD, 4), 256, 0, stream>>>(qkv, x, att);

        add_ln_k<2, 0, 1><<<NTOK, 256, 0, stream>>>(
            h, att, nullptr, nullptr, nullptr,
            ln1g + l * EDIM, ln1b + l * EDIM, nullptr, ub);

        gemm256_k<1, 0><<<dim3((NTOK / 256) * (4 * EDIM / 256), 1), 512, 0, stream>>>(
            ub, wfcT + (size_t)l * 4 * EDIM * EDIM, bfc + (size_t)l * 4 * EDIM,
            tb, nullptr, nullptr, nullptr, nullptr, NTOK, 4 * EDIM, EDIM);

        if (split4) {
            // proj: 8-phase 256^2 split-K=4 -> mb, att, p2f, p3f
            gemm256_k<0, 1><<<dim3((NTOK / 256) * (EDIM / 256), 4), 512, 0, stream>>>(
                tb, wpjT + (size_t)l * 4 * EDIM * EDIM, bproj + (size_t)l * EDIM,
                nullptr, mb, att, p2f, p3f, NTOK, EDIM, 4 * EDIM);
            add_ln_k<5, 1, 1><<<NTOK, 256, 0, stream>>>(
                mb, att, p2f, p3f, h,
                ln2g + l * EDIM, ln2b + l * EDIM, h, hb);
        } else {
            gemm_bt_k<0, 0><<<dim3(EDIM / 128, NTOK / 128, 2), 256, 0, stream>>>(
                tb, wpjT + (size_t)l * 4 * EDIM * EDIM, bproj + (size_t)l * EDIM,
                mb, att, NTOK, EDIM, 4 * EDIM);
            add_ln_k<3, 1, 1><<<NTOK, 256, 0, stream>>>(
                mb, att, h, nullptr, nullptr,
                ln2g + l * EDIM, ln2b + l * EDIM, h, hb);
        }
    }

    add_ln_k<1, 1, 0><<<NTOK, 256, 0, stream>>>(
        h, nullptr, nullptr, nullptr, nullptr, lnfg, lnfb, (float*)d_out, nullptr);
}